// Round 7
// baseline (1231.606 us; speedup 1.0000x reference)
//
#include <hip/hip_runtime.h>
#include <hip/hip_bf16.h>
#include <stdint.h>

// Problem constants
#define BATCH 4
#define NPTS  8192
#define KNN   24
#define DPT   32     // D_POINTS
#define DM    64     // D_MODEL
#define PED   60     // PE_DIM
#define DK    (DM*KNN)      // 1536
#define ROWS  (BATCH*NPTS)  // 32768

// KNN spatial grid
#define GRIDN 16
#define NCELL (GRIDN*GRIDN*GRIDN)   // 4096
#define CH    0.0625f               // cell width = 1/16 (exact in fp32)

typedef __attribute__((ext_vector_type(8))) short short8;
typedef __attribute__((ext_vector_type(4))) float f32x4;
typedef __attribute__((address_space(3))) unsigned lds_u32;
typedef const __attribute__((address_space(1))) unsigned gbl_u32;

#define WSYNC() __builtin_amdgcn_wave_barrier()

static __device__ __forceinline__ unsigned short f2bf(float f) {
  __hip_bfloat16 h = __float2bfloat16(f);
  return *(unsigned short*)&h;
}
static __device__ __forceinline__ float bf2f(unsigned short u) {
  return __uint_as_float(((unsigned)u) << 16);
}

static __device__ __forceinline__ int cell_coord(float p) {
  int c = (int)(p * (float)GRIDN);
  c = (c < 0) ? 0 : c;
  c = (c > GRIDN - 1) ? GRIDN - 1 : c;
  return c;
}

// ---------------------------------------------------------------------------
// K1: x = features @ W1.T + b1     [ROWS,32] x [64,32]^T -> [ROWS,64]
// ---------------------------------------------------------------------------
__global__ __launch_bounds__(256) void fc1_kernel(
    const float* __restrict__ f, const float* __restrict__ W1,
    const float* __restrict__ b1, float* __restrict__ x) {
  int gid = blockIdx.x * 256 + threadIdx.x;
  int n = gid >> 6, c = gid & 63;
  const float* fr = f + (size_t)n * DPT;
  const float* wr = W1 + c * DPT;
  float acc = b1[c];
#pragma unroll
  for (int i = 0; i < DPT; ++i) acc = fmaf(fr[i], wr[i], acc);
  x[(size_t)n * DM + c] = acc;
}

// ---------------------------------------------------------------------------
// K2a: build per-batch uniform grid over [0,1]^3.
// Scatter writes float4 {x,y,z,bitcast(local idx)} in cell-sorted order:
// the KNN hot loop then needs ONE dwordx4 load per candidate.
// ---------------------------------------------------------------------------
__global__ __launch_bounds__(256) void grid_build_kernel(
    const float* __restrict__ xyz, int* __restrict__ cellStart,
    float4* __restrict__ xyzi) {
  __shared__ int cnt[NCELL];     // 16 KB
  __shared__ int partial[256];
  int b = blockIdx.x, tid = threadIdx.x;
  const float* P = xyz + (size_t)b * NPTS * 3;

  for (int i = tid; i < NCELL; i += 256) cnt[i] = 0;
  __syncthreads();
  for (int i = tid; i < NPTS; i += 256) {
    int cx = cell_coord(P[3 * i + 0]);
    int cy = cell_coord(P[3 * i + 1]);
    int cz = cell_coord(P[3 * i + 2]);
    atomicAdd(&cnt[(cx << 8) | (cy << 4) | cz], 1);
  }
  __syncthreads();
  int base = tid * 16, s = 0;
#pragma unroll
  for (int j = 0; j < 16; ++j) s += cnt[base + j];
  partial[tid] = s;
  __syncthreads();
  if (tid == 0) {
    int acc = 0;
    for (int i = 0; i < 256; ++i) { int v = partial[i]; partial[i] = acc; acc += v; }
  }
  __syncthreads();
  int acc = partial[tid];
#pragma unroll
  for (int j = 0; j < 16; ++j) {
    int c = cnt[base + j];
    cnt[base + j] = acc;                          // becomes scatter cursor
    cellStart[b * (NCELL + 1) + base + j] = acc;  // exclusive start
    acc += c;
  }
  if (tid == 255) cellStart[b * (NCELL + 1) + NCELL] = NPTS;
  __syncthreads();
  for (int i = tid; i < NPTS; i += 256) {
    float px = P[3 * i + 0], py = P[3 * i + 1], pz = P[3 * i + 2];
    int cx = cell_coord(px), cy = cell_coord(py), cz = cell_coord(pz);
    int pos = atomicAdd(&cnt[(cx << 8) | (cy << 4) | cz], 1);
    float4 v;
    v.x = px; v.y = py; v.z = pz; v.w = __int_as_float(i);
    xyzi[(size_t)b * NPTS + pos] = v;
  }
}

// ---------------------------------------------------------------------------
// K2b: exact KNN via expanding cell shells + per-cell ball pruning.
// SEGMENTS-IN-WAVE 4-way split: lane = (query, seg); block 256 = 64 queries
// x 4 segments. Segment s scans points ii = s0+s, step 4 of each cell ->
// the 4 lanes of a query-group load CONSECUTIVE float4s (64B coalesced),
// each point scanned by exactly one segment (index parity partition).
// Per-segment lim pruning/stop conservative (lim_s >= merged 24th) ->
// merged result exact. Distance metric IDENTICAL to verified kernel
// (f32 diffs, f64 squares, packed (f32bits<<32)|idx keys).
// ---------------------------------------------------------------------------
__global__ __launch_bounds__(256) void grid_knn_kernel(
    const float4* __restrict__ xyzi, const int* __restrict__ cellStart,
    int* __restrict__ knn) {
  __shared__ unsigned long long sKeys[256][KNN];   // 48 KB
  int tid = threadIdx.x;
  int s = tid & 3, ql = tid >> 2;        // segment, block-local query
  int qpos = blockIdx.x * 64 + ql;       // sorted position
  int b = qpos >> 13, j = qpos & 8191;
  const int* cs = cellStart + b * (NCELL + 1);
  const float4* X = xyzi + (size_t)b * NPTS;

  float4 qv = X[j];
  float qx = qv.x, qy = qv.y, qz = qv.z;
  int cx = cell_coord(qx), cy = cell_coord(qy), cz = cell_coord(qz);

  unsigned long long key[KNN];
#pragma unroll
  for (int o = 0; o < KNN; ++o) key[o] = 0x7F800000FFFFFFFFULL;
  float lim = __builtin_inff();

  for (int rho = 0; rho <= GRIDN - 1; ++rho) {
    for (int dz = -rho; dz <= rho; ++dz) {
      int iz = cz + dz;
      if ((unsigned)iz >= GRIDN) continue;
      bool zface = (dz == -rho) || (dz == rho);
      for (int dy = -rho; dy <= rho; ++dy) {
        int iy = cy + dy;
        if ((unsigned)iy >= GRIDN) continue;
        bool face = zface || (dy == -rho) || (dy == rho);
        int dxstep = (rho == 0 || face) ? 1 : (2 * rho);
        for (int dx = -rho; dx <= rho; dx += dxstep) {
          int ix = cx + dx;
          if ((unsigned)ix >= GRIDN) continue;
          float bx = ix * CH, by = iy * CH, bz = iz * CH;
          float ex = fmaxf(fmaxf(bx - qx, qx - (bx + CH)), 0.f);
          float ey = fmaxf(fmaxf(by - qy, qy - (by + CH)), 0.f);
          float ez = fmaxf(fmaxf(bz - qz, qz - (bz + CH)), 0.f);
          float dsq = ex * ex + ey * ey + ez * ez;
          if (dsq * 0.99999f >= lim) continue;   // cannot beat current 24th
          int cid = (ix << 8) | (iy << 4) | iz;
          int s0 = cs[cid], s1 = cs[cid + 1];
          for (int ii = s0 + s; ii < s1; ii += 4) {
            float4 c4 = X[ii];
            float ddx = qx - c4.x;
            float ddy = qy - c4.y;
            float ddz = qz - c4.z;
            double dd = (double)ddx * (double)ddx + (double)ddy * (double)ddy
                      + (double)ddz * (double)ddz;
            float df = (float)dd;
            if (df < lim) {
              unsigned long long v =
                  ((unsigned long long)__float_as_uint(df) << 32)
                  | (unsigned)__float_as_int(c4.w);
#pragma unroll
              for (int tt = 0; tt < KNN; ++tt) {
                bool take = v < key[tt];
                unsigned long long old = key[tt];
                key[tt] = take ? v : key[tt];
                v = take ? old : v;
              }
              lim = __uint_as_float((unsigned)(key[KNN - 1] >> 32));
            }
          }
        }
      }
    }
    float rb = rho * CH;
    if (lim < rb * rb * 0.999999f) break;
  }
#pragma unroll
  for (int o = 0; o < KNN; ++o) sKeys[tid][o] = key[o];
  __syncthreads();
  if (tid < 64) {                // one thread per query: 4-way sorted merge
    int qpos2 = blockIdx.x * 64 + tid;
    int b2 = qpos2 >> 13, j2 = qpos2 & 8191;
    float4 qv2 = xyzi[(size_t)b2 * NPTS + j2];
    int n = (b2 << 13) + __float_as_int(qv2.w);
    int i0 = 0, i1 = 0, i2 = 0, i3 = 0;
    for (int o = 0; o < KNN; ++o) {
      unsigned long long a = sKeys[tid * 4 + 0][i0];
      unsigned long long bb = sKeys[tid * 4 + 1][i1];
      unsigned long long c = sKeys[tid * 4 + 2][i2];
      unsigned long long d = sKeys[tid * 4 + 3][i3];
      bool ab = a < bb;  unsigned long long m1 = ab ? a : bb;
      bool cd = c < d;   unsigned long long m2 = cd ? c : d;
      bool md = m1 < m2; unsigned long long mv = md ? m1 : m2;
      knn[(size_t)n * KNN + o] = (int)(unsigned)mv;
      if (md) { if (ab) ++i0; else ++i1; }
      else    { if (cd) ++i2; else ++i3; }
    }
  }
}

// ---------------------------------------------------------------------------
__device__ __forceinline__ float pe_elem(int t, float gx, float gy, float gz) {
  const float OM[10] = {1.0f, 0.3981071705534972f, 0.15848931924611134f,
                        0.06309573444801933f, 0.025118864315095794f, 0.01f,
                        0.003981071705534973f, 0.001584893192461114f,
                        0.0006309573444801933f, 0.00025118864315095795f};
  int a = t / 20, r = t % 20;
  float g = (a == 0) ? gx : ((a == 1) ? gy : gz);
  float ang = g * OM[r % 10];
  return (r < 10) ? __sinf(ang) : __cosf(ang);
}

// ---------------------------------------------------------------------------
// Shared MFMA MLP machinery (per-wave, one query per wave).
// scr: PE bf16 [32][64] swizzled -> H bf16 swizzled -> P bf16 [32][68] linear.
// ---------------------------------------------------------------------------
static __device__ __forceinline__ void pe_fill(
    unsigned short* scr, const float* __restrict__ xyz, const int* idxArr,
    int base, float qx, float qy, float qz, int ln) {
  for (int k = 0; k < KNN; ++k) {
    int gidx = base + idxArr[k];
    float gx = qx - xyz[(size_t)gidx * 3 + 0];
    float gy = qy - xyz[(size_t)gidx * 3 + 1];
    float gz = qz - xyz[(size_t)gidx * 3 + 2];
    float v = (ln < PED) ? pe_elem(ln, gx, gy, gz) : 0.f;
    scr[(k * 64 + ln) ^ ((k & 7) << 3)] = f2bf(v);
  }
#pragma unroll
  for (int k = KNN; k < 32; ++k)
    scr[(k * 64 + ln) ^ ((k & 7) << 3)] = 0;
  WSYNC();
}

static __device__ __forceinline__ short8 lds_read8(const unsigned short* p) {
  return *(const short8*)p;
}

static __device__ __forceinline__ void mlp_wave(
    unsigned short* scr, const unsigned short* w1b, const unsigned short* w2b,
    const float* __restrict__ bd1, const float* __restrict__ bd2, int ln) {
  int lrow = ln & 15, lq = ln >> 4;
  short8 af[2][2], bfr[4][2];
  f32x4 acc[2][4];

  // ---- layer 1: H = relu(PE @ Wd1^T + bd1)
#pragma unroll
  for (int mt = 0; mt < 2; ++mt)
#pragma unroll
    for (int ks = 0; ks < 2; ++ks) {
      int row = mt * 16 + lrow;
      af[mt][ks] = lds_read8(scr + ((row * 64 + ks * 32 + lq * 8) ^ ((row & 7) << 3)));
    }
#pragma unroll
  for (int nt = 0; nt < 4; ++nt)
#pragma unroll
    for (int ks = 0; ks < 2; ++ks) {
      int row = nt * 16 + lrow;
      bfr[nt][ks] = lds_read8(w1b + ((row * 64 + ks * 32 + lq * 8) ^ ((row & 7) << 3)));
    }
#pragma unroll
  for (int mt = 0; mt < 2; ++mt)
#pragma unroll
    for (int nt = 0; nt < 4; ++nt) {
      f32x4 a = (f32x4){0.f, 0.f, 0.f, 0.f};
      a = __builtin_amdgcn_mfma_f32_16x16x32_bf16(af[mt][0], bfr[nt][0], a, 0, 0, 0);
      a = __builtin_amdgcn_mfma_f32_16x16x32_bf16(af[mt][1], bfr[nt][1], a, 0, 0, 0);
      acc[mt][nt] = a;
    }
  WSYNC();
#pragma unroll
  for (int mt = 0; mt < 2; ++mt)
#pragma unroll
    for (int nt = 0; nt < 4; ++nt) {
      float b1v = bd1[nt * 16 + lrow];
#pragma unroll
      for (int r = 0; r < 4; ++r) {
        int row = mt * 16 + lq * 4 + r;
        int col = nt * 16 + lrow;
        scr[(row * 64 + col) ^ ((row & 7) << 3)] =
            f2bf(fmaxf(acc[mt][nt][r] + b1v, 0.f));
      }
    }
  WSYNC();
  // ---- layer 2: P = H @ Wd2^T + bd2
#pragma unroll
  for (int mt = 0; mt < 2; ++mt)
#pragma unroll
    for (int ks = 0; ks < 2; ++ks) {
      int row = mt * 16 + lrow;
      af[mt][ks] = lds_read8(scr + ((row * 64 + ks * 32 + lq * 8) ^ ((row & 7) << 3)));
    }
#pragma unroll
  for (int nt = 0; nt < 4; ++nt)
#pragma unroll
    for (int ks = 0; ks < 2; ++ks) {
      int row = nt * 16 + lrow;
      bfr[nt][ks] = lds_read8(w2b + ((row * 64 + ks * 32 + lq * 8) ^ ((row & 7) << 3)));
    }
#pragma unroll
  for (int mt = 0; mt < 2; ++mt)
#pragma unroll
    for (int nt = 0; nt < 4; ++nt) {
      f32x4 a = (f32x4){0.f, 0.f, 0.f, 0.f};
      a = __builtin_amdgcn_mfma_f32_16x16x32_bf16(af[mt][0], bfr[nt][0], a, 0, 0, 0);
      a = __builtin_amdgcn_mfma_f32_16x16x32_bf16(af[mt][1], bfr[nt][1], a, 0, 0, 0);
      acc[mt][nt] = a;
    }
  WSYNC();
#pragma unroll
  for (int mt = 0; mt < 2; ++mt)
#pragma unroll
    for (int nt = 0; nt < 4; ++nt) {
      float b2v = bd2[nt * 16 + lrow];
#pragma unroll
      for (int r = 0; r < 4; ++r) {
        int row = mt * 16 + lq * 4 + r;
        int col = nt * 16 + lrow;
        scr[row * 68 + col] = f2bf(acc[mt][nt][r] + b2v);
      }
    }
  WSYNC();
}

// ---------------------------------------------------------------------------
// K3: pre[n] = bf16(q - kf + pos_enc) -> preOut (packed [ROWS][1536]).
// If P16 != null, also store P bf16 into attn-row upper halves.
// ---------------------------------------------------------------------------
__global__ __launch_bounds__(256) void prebuild_kernel(
    const float* __restrict__ xyz, const float* __restrict__ x,
    const int* __restrict__ knn,
    const float* __restrict__ Wd1, const float* __restrict__ bd1,
    const float* __restrict__ Wd2, const float* __restrict__ bd2,
    unsigned short* __restrict__ preOut, unsigned short* __restrict__ P16) {
  __shared__ unsigned short sW1b[4096];
  __shared__ unsigned short sW2bb[4096];
  __shared__ unsigned short sScr[4][2176];
  __shared__ int sIdx[4][KNN];
  int tid = threadIdx.x, w = tid >> 6, ln = tid & 63;
  int n = blockIdx.x * 4 + w, b = n >> 13;

  for (int q = tid; q < 4096; q += 256) {
    int row = q >> 6, kk = q & 63;
    int idx = q ^ ((row & 7) << 3);
    sW1b[idx] = (kk < PED) ? f2bf(Wd1[row * PED + kk]) : (unsigned short)0;
    sW2bb[idx] = f2bf(Wd2[q]);
  }
  if (ln < KNN) sIdx[w][ln] = knn[(size_t)n * KNN + ln];
  __syncthreads();

  float qx = xyz[(size_t)n * 3], qy = xyz[(size_t)n * 3 + 1], qz = xyz[(size_t)n * 3 + 2];
  float xq = x[(size_t)n * DM + ln];
  unsigned short* scr = &sScr[w][0];

  pe_fill(scr, xyz, &sIdx[w][0], b << 13, qx, qy, qz, ln);
  mlp_wave(scr, sW1b, sW2bb, bd1, bd2, ln);

  for (int k = 0; k < KNN; ++k) {
    int gidx = (b << 13) + sIdx[w][k];
    float kfv = x[(size_t)gidx * DM + ln];
    float p = bf2f(scr[k * 68 + ln]);
    preOut[((size_t)n * KNN + k) * DM + ln] = f2bf(xq - kfv + p);
  }
  if (P16) {
    unsigned short* pd = P16 + (size_t)n * 3072 + 1536;
#pragma unroll
    for (int k = 0; k < KNN; ++k) pd[k * 64 + ln] = scr[k * 68 + ln];
  }
}

// ---------------------------------------------------------------------------
// K4a: f32 -> bf16 convert (vectorized) — Wa only.
// ---------------------------------------------------------------------------
__global__ __launch_bounds__(256) void conv_bf16_kernel(
    const float* __restrict__ src, unsigned short* __restrict__ dst, int n4) {
  int i = blockIdx.x * 256 + threadIdx.x;
  if (i < n4) {
    float4 v = ((const float4*)src)[i];
    ushort4 o;
    o.x = f2bf(v.x); o.y = f2bf(v.y); o.z = f2bf(v.z); o.w = f2bf(v.w);
    ((ushort4*)dst)[i] = o;
  }
}

// 16B copy kernel (fallback path only)
__global__ __launch_bounds__(256) void copy16_kernel(
    const uint4* __restrict__ src, uint4* __restrict__ dst, int nvec) {
  int i = blockIdx.x * 256 + threadIdx.x;
  if (i < nvec) dst[i] = src[i];
}

// ---------------------------------------------------------------------------
// K4b: logits(bf16) = pre_bf16 @ Wa_bf16.T + ba. 128x128 tiles, 12 n-tiles.
// TRIPLE-BUFFERED pipeline: stage K-tile t+2 at iter t; counted vmcnt(4)
// + raw s_barrier — loads stay in flight across barriers.
// Bijective XCD-chunked swizzle for A-panel L2 locality.
// ---------------------------------------------------------------------------
__global__ __launch_bounds__(256) void gemm_bf16_kernel(
    const unsigned short* __restrict__ A,   // [cr][1536] bf16 packed
    const unsigned short* __restrict__ B,   // Wa bf16 [1536][1536]
    const float* __restrict__ ba,
    unsigned short* __restrict__ Cb) {      // bf16, row pitch 3072 ushorts
  __shared__ unsigned short sA[3][4096];    // 3 x 8 KB
  __shared__ unsigned short sB[3][4096];
  unsigned nwg = gridDim.x, orig = blockIdx.x;
  unsigned xcd = orig & 7u, qd = nwg >> 3, rr = nwg & 7u;
  unsigned wgid = (xcd < rr ? xcd * (qd + 1) : rr * (qd + 1) + (xcd - rr) * qd)
                + (orig >> 3);
  int mt = wgid / 12, nt = wgid % 12;
  int m0 = mt * 128, n0 = nt * 128;
  int tid = threadIdx.x, w = tid >> 6, L = tid & 63;
  int wr = w >> 1, wc = w & 1;
  int lrow = L & 15, lq = L >> 4;

  const unsigned short* gA0 = A + (size_t)(m0 + (w * 2) * 16 + lrow) * DK + lq * 8;
  const unsigned short* gB0 = B + (size_t)(n0 + (w * 2) * 16 + lrow) * DK + lq * 8;

  f32x4 acc[4][4];
#pragma unroll
  for (int i = 0; i < 4; ++i)
#pragma unroll
    for (int j = 0; j < 4; ++j) acc[i][j] = (f32x4){0.f, 0.f, 0.f, 0.f};

#define STAGE(buf, kt)                                                        \
  {                                                                           \
    __builtin_amdgcn_global_load_lds((gbl_u32*)(gA0 + (kt)),                  \
        (lds_u32*)(&sA[(buf)][(w * 2) * 512]), 16, 0, 0);                     \
    __builtin_amdgcn_global_load_lds((gbl_u32*)(gB0 + (kt)),                  \
        (lds_u32*)(&sB[(buf)][(w * 2) * 512]), 16, 0, 0);                     \
    __builtin_amdgcn_global_load_lds((gbl_u32*)(gA0 + (size_t)16 * DK + (kt)),\
        (lds_u32*)(&sA[(buf)][(w * 2 + 1) * 512]), 16, 0, 0);                 \
    __builtin_amdgcn_global_load_lds((gbl_u32*)(gB0 + (size_t)16 * DK + (kt)),\
        (lds_u32*)(&sB[(buf)][(w * 2 + 1) * 512]), 16, 0, 0);                 \
  }

  STAGE(0, 0);
  STAGE(1, 32);

  const int nk = DK / 32;                  // 48
  for (int ki = 0; ki < nk; ++ki) {
    int cur = ki % 3;
    if (ki + 1 < nk) {
      asm volatile("s_waitcnt vmcnt(4)" ::: "memory");
    } else {
      asm volatile("s_waitcnt vmcnt(0)" ::: "memory");
    }
    __builtin_amdgcn_s_barrier();
    asm volatile("" ::: "memory");
    if (ki + 2 < nk) STAGE((ki + 2) % 3, (ki + 2) * 32);
    short8 af[4], bf4[4];
#pragma unroll
    for (int i = 0; i < 4; ++i)
      af[i] = *(const short8*)(&sA[cur][((wr * 4 + i) * 64 + L) * 8]);
#pragma unroll
    for (int j = 0; j < 4; ++j)
      bf4[j] = *(const short8*)(&sB[cur][((wc * 4 + j) * 64 + L) * 8]);
#pragma unroll
    for (int i = 0; i < 4; ++i)
#pragma unroll
      for (int j = 0; j < 4; ++j)
        acc[i][j] = __builtin_amdgcn_mfma_f32_16x16x32_bf16(af[i], bf4[j], acc[i][j], 0, 0, 0);
  }
#undef STAGE

#pragma unroll
  for (int j = 0; j < 4; ++j) {
    int col = n0 + (wc * 4 + j) * 16 + lrow;
    float bav = ba[col];
#pragma unroll
    for (int i = 0; i < 4; ++i) {
      int rbase = m0 + (wr * 4 + i) * 16 + lq * 4;
#pragma unroll
      for (int r = 0; r < 4; ++r)
        Cb[(size_t)(rbase + r) * 3072 + col] = f2bf(acc[i][j][r] + bav);
    }
  }
}

// ---------------------------------------------------------------------------
// K5-lean (big-ws): softmax over K from bf16 logits (attn-row lower half),
// P from upper half; einsum + fc2 + residual; write f32 attn over the row.
// ---------------------------------------------------------------------------
__global__ __launch_bounds__(256) void finish_kernel(
    const float* __restrict__ x, const int* __restrict__ knn,
    const float* __restrict__ W2, const float* __restrict__ b2,
    const unsigned short* attn16, float* attnF, float* __restrict__ res) {
  __shared__ float sW2f[DM][DM + 1];
  __shared__ float sRes[4][64];
  __shared__ int sIdx[4][KNN];
  int tid = threadIdx.x, w = tid >> 6, ln = tid & 63;
  int n = blockIdx.x * 4 + w, b = n >> 13;

  for (int q = tid; q < DM * DM; q += 256) sW2f[q >> 6][q & 63] = W2[q];
  if (ln < KNN) sIdx[w][ln] = knn[(size_t)n * KNN + ln];
  __syncthreads();

  const unsigned short* lrow = attn16 + (size_t)n * 3072;
  float L[KNN], Pv[KNN];
#pragma unroll
  for (int k = 0; k < KNN; ++k) L[k] = bf2f(lrow[k * 64 + ln]);
#pragma unroll
  for (int k = 0; k < KNN; ++k) Pv[k] = bf2f(lrow[1536 + k * 64 + ln]);
  asm volatile("" ::: "memory");   // all reads of row n before any write

  float mx = -__builtin_inff();
#pragma unroll
  for (int k = 0; k < KNN; ++k) mx = fmaxf(mx, L[k]);
  float ssum = 0.f;
#pragma unroll
  for (int k = 0; k < KNN; ++k) { L[k] = __expf((L[k] - mx) * 0.125f); ssum += L[k]; }
  float inv = 1.0f / ssum;
#pragma unroll
  for (int k = 0; k < KNN; ++k) {
    L[k] *= inv;
    attnF[(size_t)n * DK + k * 64 + ln] = L[k];
  }

  float racc = 0.f;
  for (int k = 0; k < KNN; ++k) {
    int gidx = (b << 13) + sIdx[w][k];
    float xv = x[(size_t)gidx * DM + ln];
    racc = fmaf(L[k], xv + Pv[k], racc);
  }
  sRes[w][ln] = racc;
  WSYNC();
  float oacc = b2[ln] + x[(size_t)n * DM + ln];
#pragma unroll
  for (int o = 0; o < DM; ++o) oacc = fmaf(sRes[w][o], sW2f[ln][o], oacc);
  res[(size_t)n * DM + ln] = oacc;
}

// ---------------------------------------------------------------------------
// K5-full (small-ws fallback): recompute MLP via MFMA, bf16 logits in.
// ---------------------------------------------------------------------------
__global__ __launch_bounds__(256) void finish_full_kernel(
    const float* __restrict__ xyz, const float* __restrict__ x,
    const int* __restrict__ knn,
    const float* __restrict__ Wd1, const float* __restrict__ bd1,
    const float* __restrict__ Wd2, const float* __restrict__ bd2,
    const float* __restrict__ W2, const float* __restrict__ b2,
    const unsigned short* attn16, float* attnF, float* __restrict__ res) {
  __shared__ unsigned short sW1b[4096];
  __shared__ unsigned short sW2bb[4096];
  __shared__ float sW2f[DM][DM + 1];
  __shared__ unsigned short sScr[4][2176];
  __shared__ float sRes[4][64];
  __shared__ int sIdx[4][KNN];
  int tid = threadIdx.x, w = tid >> 6, ln = tid & 63;
  int n = blockIdx.x * 4 + w, b = n >> 13;

  for (int q = tid; q < 4096; q += 256) {
    int row = q >> 6, kk = q & 63;
    int idx = q ^ ((row & 7) << 3);
    sW1b[idx] = (kk < PED) ? f2bf(Wd1[row * PED + kk]) : (unsigned short)0;
    sW2bb[idx] = f2bf(Wd2[q]);
  }
  for (int q = tid; q < DM * DM; q += 256) sW2f[q >> 6][q & 63] = W2[q];
  if (ln < KNN) sIdx[w][ln] = knn[(size_t)n * KNN + ln];
  __syncthreads();

  float qx = xyz[(size_t)n * 3], qy = xyz[(size_t)n * 3 + 1], qz = xyz[(size_t)n * 3 + 2];
  unsigned short* scr = &sScr[w][0];
  pe_fill(scr, xyz, &sIdx[w][0], b << 13, qx, qy, qz, ln);
  mlp_wave(scr, sW1b, sW2bb, bd1, bd2, ln);

  const unsigned short* lrow = attn16 + (size_t)n * 3072;
  float L[KNN];
#pragma unroll
  for (int k = 0; k < KNN; ++k) L[k] = bf2f(lrow[k * 64 + ln]);
  asm volatile("" ::: "memory");
  float mx = -__builtin_inff();
#pragma unroll
  for (int k = 0; k < KNN; ++k) mx = fmaxf(mx, L[k]);
  float ssum = 0.f;
#pragma unroll
  for (int k = 0; k < KNN; ++k) { L[k] = __expf((L[k] - mx) * 0.125f); ssum += L[k]; }
  float inv = 1.0f / ssum;
#pragma unroll
  for (int k = 0; k < KNN; ++k) {
    L[k] *= inv;
    attnF[(size_t)n * DK + k * 64 + ln] = L[k];
  }
  float racc = 0.f;
  for (int k = 0; k < KNN; ++k) {
    int gidx = (b << 13) + sIdx[w][k];
    float xv = x[(size_t)gidx * DM + ln];
    racc = fmaf(L[k], xv + bf2f(scr[k * 68 + ln]), racc);
  }
  sRes[w][ln] = racc;
  WSYNC();
  float oacc = b2[ln] + x[(size_t)n * DM + ln];
#pragma unroll
  for (int o = 0; o < DM; ++o) oacc = fmaf(sRes[w][o], sW2f[ln][o], oacc);
  res[(size_t)n * DM + ln] = oacc;
}

// ---------------------------------------------------------------------------
extern "C" void kernel_launch(void* const* d_in, const int* in_sizes, int n_in,
                              void* d_out, int out_size, void* d_ws, size_t ws_size,
                              hipStream_t stream) {
  const float* features = (const float*)d_in[0];
  const float* xyz = (const float*)d_in[1];
  const float* W1  = (const float*)d_in[2];
  const float* b1  = (const float*)d_in[3];
  const float* W2  = (const float*)d_in[4];
  const float* b2  = (const float*)d_in[5];
  const float* Wd1 = (const float*)d_in[6];
  const float* bd1 = (const float*)d_in[7];
  const float* Wd2 = (const float*)d_in[8];
  const float* bd2 = (const float*)d_in[9];
  const float* Wa  = (const float*)d_in[10];
  const float* ba  = (const float*)d_in[11];

  float* res  = (float*)d_out;                      // [ROWS*64]
  float* attn = (float*)d_out + (size_t)ROWS * DM;  // [ROWS*1536] f32 region
  unsigned short* attn16 = (unsigned short*)attn;   // bf16 view (pitch 3072/row)

  size_t xB   = (size_t)ROWS * DM * 4;              // 8,388,608
  size_t WaB  = (size_t)DK * DK * 2;                // 4,718,592
  size_t used = xB + (size_t)ROWS * KNN * 4;
  float* xbuf = (float*)d_ws;
  int*   knn  = (int*)((char*)d_ws + xB);

  size_t avail = (ws_size > used) ? ws_size - used : 0;
  size_t rowB = (size_t)DK * 2;                     // bf16 row = 3072 B
  bool bigws = avail >= WaB + (size_t)ROWS * rowB;  // 105.4 MB

  // Grid scratch at attn head (16B-aligned); fully consumed by grid_knn
  // before prebuild first writes to the attn region (stream-ordered).
  float4* xyzi = (float4*)attn;                     // [BATCH*NPTS] = 512 KB
  int* gridCS  = (int*)(xyzi + (size_t)BATCH * NPTS);

  hipLaunchKernelGGL(fc1_kernel, dim3(ROWS * DM / 256), dim3(256), 0, stream,
                     features, W1, b1, xbuf);
  hipLaunchKernelGGL(grid_build_kernel, dim3(BATCH), dim3(256), 0, stream,
                     xyz, gridCS, xyzi);
  hipLaunchKernelGGL(grid_knn_kernel, dim3(ROWS / 64), dim3(256), 0, stream,
                     xyzi, gridCS, knn);

  if (bigws) {
    unsigned short* WaBf = (unsigned short*)((char*)d_ws + used);
    unsigned short* preW = (unsigned short*)((char*)d_ws + used + WaB); // 100.7MB
    hipLaunchKernelGGL(prebuild_kernel, dim3(ROWS / 4), dim3(256), 0, stream,
                       xyz, xbuf, knn, Wd1, bd1, Wd2, bd2, preW, attn16);
    {
      int n4 = DK * DK / 4;
      hipLaunchKernelGGL(conv_bf16_kernel, dim3((n4 + 255) / 256), dim3(256), 0, stream,
                         Wa, WaBf, n4);
    }
    hipLaunchKernelGGL(gemm_bf16_kernel, dim3((ROWS / 128) * 12), dim3(256), 0, stream,
                       preW, WaBf, ba, attn16);
    hipLaunchKernelGGL(finish_kernel, dim3(ROWS / 4), dim3(256), 0, stream,
                       xbuf, knn, W2, b2, attn16, attn, res);
  } else {
    unsigned short* WaBf  = (unsigned short*)d_out;
    unsigned short* chunk = (unsigned short*)((char*)d_out + WaB);
    int chunk_rows = (int)((xB - WaB) / rowB) & ~127;   // 1152
    hipLaunchKernelGGL(prebuild_kernel, dim3(ROWS / 4), dim3(256), 0, stream,
                       xyz, xbuf, knn, Wd1, bd1, Wd2, bd2, attn16,
                       (unsigned short*)nullptr);
    {
      int n4 = DK * DK / 4;
      hipLaunchKernelGGL(conv_bf16_kernel, dim3((n4 + 255) / 256), dim3(256), 0, stream,
                         Wa, WaBf, n4);
    }
    {
      int cr0 = (chunk_rows < ROWS) ? chunk_rows : ROWS;
      int nvec = cr0 * (DK * 2 / 16);
      hipLaunchKernelGGL(copy16_kernel, dim3((nvec + 255) / 256), dim3(256), 0, stream,
                         (const uint4*)attn16, (uint4*)chunk, nvec);
    }
    int top = ((ROWS - 1) / chunk_rows) * chunk_rows;
    for (int r0 = top; r0 >= 0; r0 -= chunk_rows) {
      int cr = (ROWS - r0 < chunk_rows) ? (ROWS - r0) : chunk_rows;
      const unsigned short* Aptr =
          (r0 == 0) ? chunk : attn16 + (size_t)r0 * DK;
      hipLaunchKernelGGL(gemm_bf16_kernel, dim3((cr / 128) * 12), dim3(256), 0, stream,
                         Aptr, WaBf, ba, attn16 + (size_t)r0 * 3072);
    }
    hipLaunchKernelGGL(finish_full_kernel, dim3(ROWS / 4), dim3(256), 0, stream,
                       xyz, xbuf, knn, Wd1, bd1, Wd2, bd2, W2, b2,
                       attn16, attn, res);
  }
}

// Round 8
// 939.298 us; speedup vs baseline: 1.3112x; 1.3112x over previous
//
#include <hip/hip_runtime.h>
#include <hip/hip_bf16.h>
#include <stdint.h>

// Problem constants
#define BATCH 4
#define NPTS  8192
#define KNN   24
#define DPT   32     // D_POINTS
#define DM    64     // D_MODEL
#define PED   60     // PE_DIM
#define DK    (DM*KNN)      // 1536
#define ROWS  (BATCH*NPTS)  // 32768

// KNN spatial grid
#define GRIDN 16
#define NCELL (GRIDN*GRIDN*GRIDN)   // 4096
#define CH    0.0625f               // cell width = 1/16 (exact in fp32)

typedef __attribute__((ext_vector_type(8))) short short8;
typedef __attribute__((ext_vector_type(4))) float f32x4;
typedef __attribute__((address_space(3))) unsigned lds_u32;
typedef const __attribute__((address_space(1))) unsigned gbl_u32;

#define WSYNC() __builtin_amdgcn_wave_barrier()

static __device__ __forceinline__ unsigned short f2bf(float f) {
  __hip_bfloat16 h = __float2bfloat16(f);
  return *(unsigned short*)&h;
}
static __device__ __forceinline__ float bf2f(unsigned short u) {
  return __uint_as_float(((unsigned)u) << 16);
}

static __device__ __forceinline__ int cell_coord(float p) {
  int c = (int)(p * (float)GRIDN);
  c = (c < 0) ? 0 : c;
  c = (c > GRIDN - 1) ? GRIDN - 1 : c;
  return c;
}

// ---------------------------------------------------------------------------
// K1: x = features @ W1.T + b1     [ROWS,32] x [64,32]^T -> [ROWS,64]
// ---------------------------------------------------------------------------
__global__ __launch_bounds__(256) void fc1_kernel(
    const float* __restrict__ f, const float* __restrict__ W1,
    const float* __restrict__ b1, float* __restrict__ x) {
  int gid = blockIdx.x * 256 + threadIdx.x;
  int n = gid >> 6, c = gid & 63;
  const float* fr = f + (size_t)n * DPT;
  const float* wr = W1 + c * DPT;
  float acc = b1[c];
#pragma unroll
  for (int i = 0; i < DPT; ++i) acc = fmaf(fr[i], wr[i], acc);
  x[(size_t)n * DM + c] = acc;
}

// ---------------------------------------------------------------------------
// K2a: build per-batch uniform grid over [0,1]^3.
// Scatter writes float4 {x,y,z,bitcast(local idx)} in cell-sorted order:
// the KNN hot loop then needs ONE dwordx4 load per candidate.
// ---------------------------------------------------------------------------
__global__ __launch_bounds__(256) void grid_build_kernel(
    const float* __restrict__ xyz, int* __restrict__ cellStart,
    float4* __restrict__ xyzi) {
  __shared__ int cnt[NCELL];     // 16 KB
  __shared__ int partial[256];
  int b = blockIdx.x, tid = threadIdx.x;
  const float* P = xyz + (size_t)b * NPTS * 3;

  for (int i = tid; i < NCELL; i += 256) cnt[i] = 0;
  __syncthreads();
  for (int i = tid; i < NPTS; i += 256) {
    int cx = cell_coord(P[3 * i + 0]);
    int cy = cell_coord(P[3 * i + 1]);
    int cz = cell_coord(P[3 * i + 2]);
    atomicAdd(&cnt[(cx << 8) | (cy << 4) | cz], 1);
  }
  __syncthreads();
  int base = tid * 16, s = 0;
#pragma unroll
  for (int j = 0; j < 16; ++j) s += cnt[base + j];
  partial[tid] = s;
  __syncthreads();
  if (tid == 0) {
    int acc = 0;
    for (int i = 0; i < 256; ++i) { int v = partial[i]; partial[i] = acc; acc += v; }
  }
  __syncthreads();
  int acc = partial[tid];
#pragma unroll
  for (int j = 0; j < 16; ++j) {
    int c = cnt[base + j];
    cnt[base + j] = acc;                          // becomes scatter cursor
    cellStart[b * (NCELL + 1) + base + j] = acc;  // exclusive start
    acc += c;
  }
  if (tid == 255) cellStart[b * (NCELL + 1) + NCELL] = NPTS;
  __syncthreads();
  for (int i = tid; i < NPTS; i += 256) {
    float px = P[3 * i + 0], py = P[3 * i + 1], pz = P[3 * i + 2];
    int cx = cell_coord(px), cy = cell_coord(py), cz = cell_coord(pz);
    int pos = atomicAdd(&cnt[(cx << 8) | (cy << 4) | cz], 1);
    float4 v;
    v.x = px; v.y = py; v.z = pz; v.w = __int_as_float(i);
    xyzi[(size_t)b * NPTS + pos] = v;
  }
}

// ---------------------------------------------------------------------------
// K2b: exact KNN, 4-way segments-in-wave + GROUP-SHARED conservative bound.
// Lane = (query, seg); the 4 segment lanes of a query are adjacent wave
// lanes, so limg = min over group of per-segment lims costs 2 shfl_xor.
// Each lim_s is the 24th of a SUBSET of scanned points -> lim_s >= merged
// 24th >= final merged 24th, so limg is a conservative bound: using it for
// the insertion gate / cell prune / shell stop can only drop candidates
// with df >= final merged 24th (same tie-boundary semantics as the
// verified df<lim gate). limg and dsq are group-uniform -> cell skips and
// shell stops are group-convergent. Distance metric IDENTICAL to the
// verified kernel (f32 diffs, f64 squares, packed (f32bits<<32)|idx keys).
// ---------------------------------------------------------------------------
__global__ __launch_bounds__(256) void grid_knn_kernel(
    const float4* __restrict__ xyzi, const int* __restrict__ cellStart,
    int* __restrict__ knn) {
  __shared__ unsigned long long sKeys[256][KNN];   // 48 KB
  int tid = threadIdx.x;
  int s = tid & 3, ql = tid >> 2;        // segment, block-local query
  int qpos = blockIdx.x * 64 + ql;       // sorted position
  int b = qpos >> 13, j = qpos & 8191;
  const int* cs = cellStart + b * (NCELL + 1);
  const float4* X = xyzi + (size_t)b * NPTS;

  float4 qv = X[j];
  float qx = qv.x, qy = qv.y, qz = qv.z;
  int cx = cell_coord(qx), cy = cell_coord(qy), cz = cell_coord(qz);

  unsigned long long key[KNN];
#pragma unroll
  for (int o = 0; o < KNN; ++o) key[o] = 0x7F800000FFFFFFFFULL;
  float lim = __builtin_inff();

  for (int rho = 0; rho <= GRIDN - 1; ++rho) {
    for (int dz = -rho; dz <= rho; ++dz) {
      int iz = cz + dz;
      if ((unsigned)iz >= GRIDN) continue;
      bool zface = (dz == -rho) || (dz == rho);
      for (int dy = -rho; dy <= rho; ++dy) {
        int iy = cy + dy;
        if ((unsigned)iy >= GRIDN) continue;
        bool face = zface || (dy == -rho) || (dy == rho);
        int dxstep = (rho == 0 || face) ? 1 : (2 * rho);
        for (int dx = -rho; dx <= rho; dx += dxstep) {
          int ix = cx + dx;
          if ((unsigned)ix >= GRIDN) continue;
          // group-shared conservative bound (all 4 lanes converged here)
          float limg = fminf(lim, __shfl_xor(lim, 1, 64));
          limg = fminf(limg, __shfl_xor(limg, 2, 64));
          float bx = ix * CH, by = iy * CH, bz = iz * CH;
          float ex = fmaxf(fmaxf(bx - qx, qx - (bx + CH)), 0.f);
          float ey = fmaxf(fmaxf(by - qy, qy - (by + CH)), 0.f);
          float ez = fmaxf(fmaxf(bz - qz, qz - (bz + CH)), 0.f);
          float dsq = ex * ex + ey * ey + ez * ez;
          if (dsq * 0.99999f >= limg) continue;  // group-uniform skip
          int cid = (ix << 8) | (iy << 4) | iz;
          int s0 = cs[cid], s1 = cs[cid + 1];
          for (int ii = s0 + s; ii < s1; ii += 4) {
            float4 c4 = X[ii];
            float ddx = qx - c4.x;
            float ddy = qy - c4.y;
            float ddz = qz - c4.z;
            double dd = (double)ddx * (double)ddx + (double)ddy * (double)ddy
                      + (double)ddz * (double)ddz;
            float df = (float)dd;
            if (df < fminf(limg, lim)) {
              unsigned long long v =
                  ((unsigned long long)__float_as_uint(df) << 32)
                  | (unsigned)__float_as_int(c4.w);
#pragma unroll
              for (int tt = 0; tt < KNN; ++tt) {
                bool take = v < key[tt];
                unsigned long long old = key[tt];
                key[tt] = take ? v : key[tt];
                v = take ? old : v;
              }
              lim = __uint_as_float((unsigned)(key[KNN - 1] >> 32));
            }
          }
        }
      }
    }
    // group-shared stop: no unvisited point can beat the merged 24th
    float limg = fminf(lim, __shfl_xor(lim, 1, 64));
    limg = fminf(limg, __shfl_xor(limg, 2, 64));
    float rb = rho * CH;
    if (limg < rb * rb * 0.999999f) break;
  }
#pragma unroll
  for (int o = 0; o < KNN; ++o) sKeys[tid][o] = key[o];
  __syncthreads();
  if (tid < 64) {                // one thread per query: 4-way sorted merge
    int qpos2 = blockIdx.x * 64 + tid;
    int b2 = qpos2 >> 13, j2 = qpos2 & 8191;
    float4 qv2 = xyzi[(size_t)b2 * NPTS + j2];
    int n = (b2 << 13) + __float_as_int(qv2.w);
    int i0 = 0, i1 = 0, i2 = 0, i3 = 0;
    for (int o = 0; o < KNN; ++o) {
      unsigned long long a = sKeys[tid * 4 + 0][i0];
      unsigned long long bb = sKeys[tid * 4 + 1][i1];
      unsigned long long c = sKeys[tid * 4 + 2][i2];
      unsigned long long d = sKeys[tid * 4 + 3][i3];
      bool ab = a < bb;  unsigned long long m1 = ab ? a : bb;
      bool cd = c < d;   unsigned long long m2 = cd ? c : d;
      bool md = m1 < m2; unsigned long long mv = md ? m1 : m2;
      knn[(size_t)n * KNN + o] = (int)(unsigned)mv;
      if (md) { if (ab) ++i0; else ++i1; }
      else    { if (cd) ++i2; else ++i3; }
    }
  }
}

// ---------------------------------------------------------------------------
__device__ __forceinline__ float pe_elem(int t, float gx, float gy, float gz) {
  const float OM[10] = {1.0f, 0.3981071705534972f, 0.15848931924611134f,
                        0.06309573444801933f, 0.025118864315095794f, 0.01f,
                        0.003981071705534973f, 0.001584893192461114f,
                        0.0006309573444801933f, 0.00025118864315095795f};
  int a = t / 20, r = t % 20;
  float g = (a == 0) ? gx : ((a == 1) ? gy : gz);
  float ang = g * OM[r % 10];
  return (r < 10) ? __sinf(ang) : __cosf(ang);
}

// ---------------------------------------------------------------------------
// Shared MFMA MLP machinery (per-wave, one query per wave).
// scr: PE bf16 [32][64] swizzled -> H bf16 swizzled -> P bf16 [32][68] linear.
// ---------------------------------------------------------------------------
static __device__ __forceinline__ void pe_fill(
    unsigned short* scr, const float* __restrict__ xyz, const int* idxArr,
    int base, float qx, float qy, float qz, int ln) {
  for (int k = 0; k < KNN; ++k) {
    int gidx = base + idxArr[k];
    float gx = qx - xyz[(size_t)gidx * 3 + 0];
    float gy = qy - xyz[(size_t)gidx * 3 + 1];
    float gz = qz - xyz[(size_t)gidx * 3 + 2];
    float v = (ln < PED) ? pe_elem(ln, gx, gy, gz) : 0.f;
    scr[(k * 64 + ln) ^ ((k & 7) << 3)] = f2bf(v);
  }
#pragma unroll
  for (int k = KNN; k < 32; ++k)
    scr[(k * 64 + ln) ^ ((k & 7) << 3)] = 0;
  WSYNC();
}

static __device__ __forceinline__ short8 lds_read8(const unsigned short* p) {
  return *(const short8*)p;
}

static __device__ __forceinline__ void mlp_wave(
    unsigned short* scr, const unsigned short* w1b, const unsigned short* w2b,
    const float* __restrict__ bd1, const float* __restrict__ bd2, int ln) {
  int lrow = ln & 15, lq = ln >> 4;
  short8 af[2][2], bfr[4][2];
  f32x4 acc[2][4];

  // ---- layer 1: H = relu(PE @ Wd1^T + bd1)
#pragma unroll
  for (int mt = 0; mt < 2; ++mt)
#pragma unroll
    for (int ks = 0; ks < 2; ++ks) {
      int row = mt * 16 + lrow;
      af[mt][ks] = lds_read8(scr + ((row * 64 + ks * 32 + lq * 8) ^ ((row & 7) << 3)));
    }
#pragma unroll
  for (int nt = 0; nt < 4; ++nt)
#pragma unroll
    for (int ks = 0; ks < 2; ++ks) {
      int row = nt * 16 + lrow;
      bfr[nt][ks] = lds_read8(w1b + ((row * 64 + ks * 32 + lq * 8) ^ ((row & 7) << 3)));
    }
#pragma unroll
  for (int mt = 0; mt < 2; ++mt)
#pragma unroll
    for (int nt = 0; nt < 4; ++nt) {
      f32x4 a = (f32x4){0.f, 0.f, 0.f, 0.f};
      a = __builtin_amdgcn_mfma_f32_16x16x32_bf16(af[mt][0], bfr[nt][0], a, 0, 0, 0);
      a = __builtin_amdgcn_mfma_f32_16x16x32_bf16(af[mt][1], bfr[nt][1], a, 0, 0, 0);
      acc[mt][nt] = a;
    }
  WSYNC();
#pragma unroll
  for (int mt = 0; mt < 2; ++mt)
#pragma unroll
    for (int nt = 0; nt < 4; ++nt) {
      float b1v = bd1[nt * 16 + lrow];
#pragma unroll
      for (int r = 0; r < 4; ++r) {
        int row = mt * 16 + lq * 4 + r;
        int col = nt * 16 + lrow;
        scr[(row * 64 + col) ^ ((row & 7) << 3)] =
            f2bf(fmaxf(acc[mt][nt][r] + b1v, 0.f));
      }
    }
  WSYNC();
  // ---- layer 2: P = H @ Wd2^T + bd2
#pragma unroll
  for (int mt = 0; mt < 2; ++mt)
#pragma unroll
    for (int ks = 0; ks < 2; ++ks) {
      int row = mt * 16 + lrow;
      af[mt][ks] = lds_read8(scr + ((row * 64 + ks * 32 + lq * 8) ^ ((row & 7) << 3)));
    }
#pragma unroll
  for (int nt = 0; nt < 4; ++nt)
#pragma unroll
    for (int ks = 0; ks < 2; ++ks) {
      int row = nt * 16 + lrow;
      bfr[nt][ks] = lds_read8(w2b + ((row * 64 + ks * 32 + lq * 8) ^ ((row & 7) << 3)));
    }
#pragma unroll
  for (int mt = 0; mt < 2; ++mt)
#pragma unroll
    for (int nt = 0; nt < 4; ++nt) {
      f32x4 a = (f32x4){0.f, 0.f, 0.f, 0.f};
      a = __builtin_amdgcn_mfma_f32_16x16x32_bf16(af[mt][0], bfr[nt][0], a, 0, 0, 0);
      a = __builtin_amdgcn_mfma_f32_16x16x32_bf16(af[mt][1], bfr[nt][1], a, 0, 0, 0);
      acc[mt][nt] = a;
    }
  WSYNC();
#pragma unroll
  for (int mt = 0; mt < 2; ++mt)
#pragma unroll
    for (int nt = 0; nt < 4; ++nt) {
      float b2v = bd2[nt * 16 + lrow];
#pragma unroll
      for (int r = 0; r < 4; ++r) {
        int row = mt * 16 + lq * 4 + r;
        int col = nt * 16 + lrow;
        scr[row * 68 + col] = f2bf(acc[mt][nt][r] + b2v);
      }
    }
  WSYNC();
}

// ---------------------------------------------------------------------------
// K3: pre[n] = bf16(q - kf + pos_enc) -> preOut (packed [ROWS][1536]).
// If P16 != null, also store P bf16 into attn-row upper halves.
// ---------------------------------------------------------------------------
__global__ __launch_bounds__(256) void prebuild_kernel(
    const float* __restrict__ xyz, const float* __restrict__ x,
    const int* __restrict__ knn,
    const float* __restrict__ Wd1, const float* __restrict__ bd1,
    const float* __restrict__ Wd2, const float* __restrict__ bd2,
    unsigned short* __restrict__ preOut, unsigned short* __restrict__ P16) {
  __shared__ unsigned short sW1b[4096];
  __shared__ unsigned short sW2bb[4096];
  __shared__ unsigned short sScr[4][2176];
  __shared__ int sIdx[4][KNN];
  int tid = threadIdx.x, w = tid >> 6, ln = tid & 63;
  int n = blockIdx.x * 4 + w, b = n >> 13;

  for (int q = tid; q < 4096; q += 256) {
    int row = q >> 6, kk = q & 63;
    int idx = q ^ ((row & 7) << 3);
    sW1b[idx] = (kk < PED) ? f2bf(Wd1[row * PED + kk]) : (unsigned short)0;
    sW2bb[idx] = f2bf(Wd2[q]);
  }
  if (ln < KNN) sIdx[w][ln] = knn[(size_t)n * KNN + ln];
  __syncthreads();

  float qx = xyz[(size_t)n * 3], qy = xyz[(size_t)n * 3 + 1], qz = xyz[(size_t)n * 3 + 2];
  float xq = x[(size_t)n * DM + ln];
  unsigned short* scr = &sScr[w][0];

  pe_fill(scr, xyz, &sIdx[w][0], b << 13, qx, qy, qz, ln);
  mlp_wave(scr, sW1b, sW2bb, bd1, bd2, ln);

  for (int k = 0; k < KNN; ++k) {
    int gidx = (b << 13) + sIdx[w][k];
    float kfv = x[(size_t)gidx * DM + ln];
    float p = bf2f(scr[k * 68 + ln]);
    preOut[((size_t)n * KNN + k) * DM + ln] = f2bf(xq - kfv + p);
  }
  if (P16) {
    unsigned short* pd = P16 + (size_t)n * 3072 + 1536;
#pragma unroll
    for (int k = 0; k < KNN; ++k) pd[k * 64 + ln] = scr[k * 68 + ln];
  }
}

// ---------------------------------------------------------------------------
// K4a: f32 -> bf16 convert (vectorized) — Wa only.
// ---------------------------------------------------------------------------
__global__ __launch_bounds__(256) void conv_bf16_kernel(
    const float* __restrict__ src, unsigned short* __restrict__ dst, int n4) {
  int i = blockIdx.x * 256 + threadIdx.x;
  if (i < n4) {
    float4 v = ((const float4*)src)[i];
    ushort4 o;
    o.x = f2bf(v.x); o.y = f2bf(v.y); o.z = f2bf(v.z); o.w = f2bf(v.w);
    ((ushort4*)dst)[i] = o;
  }
}

// 16B copy kernel (fallback path only)
__global__ __launch_bounds__(256) void copy16_kernel(
    const uint4* __restrict__ src, uint4* __restrict__ dst, int nvec) {
  int i = blockIdx.x * 256 + threadIdx.x;
  if (i < nvec) dst[i] = src[i];
}

// ---------------------------------------------------------------------------
// K4b: logits(bf16) = pre_bf16 @ Wa_bf16.T + ba. 128x128 tiles, 12 n-tiles.
// TRIPLE-BUFFERED pipeline: stage K-tile t+2 at iter t; counted vmcnt(4)
// + raw s_barrier — loads stay in flight across barriers.
// Bijective XCD-chunked swizzle for A-panel L2 locality.
// ---------------------------------------------------------------------------
__global__ __launch_bounds__(256) void gemm_bf16_kernel(
    const unsigned short* __restrict__ A,   // [cr][1536] bf16 packed
    const unsigned short* __restrict__ B,   // Wa bf16 [1536][1536]
    const float* __restrict__ ba,
    unsigned short* __restrict__ Cb) {      // bf16, row pitch 3072 ushorts
  __shared__ unsigned short sA[3][4096];    // 3 x 8 KB
  __shared__ unsigned short sB[3][4096];
  unsigned nwg = gridDim.x, orig = blockIdx.x;
  unsigned xcd = orig & 7u, qd = nwg >> 3, rr = nwg & 7u;
  unsigned wgid = (xcd < rr ? xcd * (qd + 1) : rr * (qd + 1) + (xcd - rr) * qd)
                + (orig >> 3);
  int mt = wgid / 12, nt = wgid % 12;
  int m0 = mt * 128, n0 = nt * 128;
  int tid = threadIdx.x, w = tid >> 6, L = tid & 63;
  int wr = w >> 1, wc = w & 1;
  int lrow = L & 15, lq = L >> 4;

  const unsigned short* gA0 = A + (size_t)(m0 + (w * 2) * 16 + lrow) * DK + lq * 8;
  const unsigned short* gB0 = B + (size_t)(n0 + (w * 2) * 16 + lrow) * DK + lq * 8;

  f32x4 acc[4][4];
#pragma unroll
  for (int i = 0; i < 4; ++i)
#pragma unroll
    for (int j = 0; j < 4; ++j) acc[i][j] = (f32x4){0.f, 0.f, 0.f, 0.f};

#define STAGE(buf, kt)                                                        \
  {                                                                           \
    __builtin_amdgcn_global_load_lds((gbl_u32*)(gA0 + (kt)),                  \
        (lds_u32*)(&sA[(buf)][(w * 2) * 512]), 16, 0, 0);                     \
    __builtin_amdgcn_global_load_lds((gbl_u32*)(gB0 + (kt)),                  \
        (lds_u32*)(&sB[(buf)][(w * 2) * 512]), 16, 0, 0);                     \
    __builtin_amdgcn_global_load_lds((gbl_u32*)(gA0 + (size_t)16 * DK + (kt)),\
        (lds_u32*)(&sA[(buf)][(w * 2 + 1) * 512]), 16, 0, 0);                 \
    __builtin_amdgcn_global_load_lds((gbl_u32*)(gB0 + (size_t)16 * DK + (kt)),\
        (lds_u32*)(&sB[(buf)][(w * 2 + 1) * 512]), 16, 0, 0);                 \
  }

  STAGE(0, 0);
  STAGE(1, 32);

  const int nk = DK / 32;                  // 48
  for (int ki = 0; ki < nk; ++ki) {
    int cur = ki % 3;
    if (ki + 1 < nk) {
      asm volatile("s_waitcnt vmcnt(4)" ::: "memory");
    } else {
      asm volatile("s_waitcnt vmcnt(0)" ::: "memory");
    }
    __builtin_amdgcn_s_barrier();
    asm volatile("" ::: "memory");
    if (ki + 2 < nk) STAGE((ki + 2) % 3, (ki + 2) * 32);
    short8 af[4], bf4[4];
#pragma unroll
    for (int i = 0; i < 4; ++i)
      af[i] = *(const short8*)(&sA[cur][((wr * 4 + i) * 64 + L) * 8]);
#pragma unroll
    for (int j = 0; j < 4; ++j)
      bf4[j] = *(const short8*)(&sB[cur][((wc * 4 + j) * 64 + L) * 8]);
#pragma unroll
    for (int i = 0; i < 4; ++i)
#pragma unroll
      for (int j = 0; j < 4; ++j)
        acc[i][j] = __builtin_amdgcn_mfma_f32_16x16x32_bf16(af[i], bf4[j], acc[i][j], 0, 0, 0);
  }
#undef STAGE

#pragma unroll
  for (int j = 0; j < 4; ++j) {
    int col = n0 + (wc * 4 + j) * 16 + lrow;
    float bav = ba[col];
#pragma unroll
    for (int i = 0; i < 4; ++i) {
      int rbase = m0 + (wr * 4 + i) * 16 + lq * 4;
#pragma unroll
      for (int r = 0; r < 4; ++r)
        Cb[(size_t)(rbase + r) * 3072 + col] = f2bf(acc[i][j][r] + bav);
    }
  }
}

// ---------------------------------------------------------------------------
// K5-lean (big-ws): softmax over K from bf16 logits (attn-row lower half),
// P from upper half; einsum + fc2 + residual; write f32 attn over the row.
// ---------------------------------------------------------------------------
__global__ __launch_bounds__(256) void finish_kernel(
    const float* __restrict__ x, const int* __restrict__ knn,
    const float* __restrict__ W2, const float* __restrict__ b2,
    const unsigned short* attn16, float* attnF, float* __restrict__ res) {
  __shared__ float sW2f[DM][DM + 1];
  __shared__ float sRes[4][64];
  __shared__ int sIdx[4][KNN];
  int tid = threadIdx.x, w = tid >> 6, ln = tid & 63;
  int n = blockIdx.x * 4 + w, b = n >> 13;

  for (int q = tid; q < DM * DM; q += 256) sW2f[q >> 6][q & 63] = W2[q];
  if (ln < KNN) sIdx[w][ln] = knn[(size_t)n * KNN + ln];
  __syncthreads();

  const unsigned short* lrow = attn16 + (size_t)n * 3072;
  float L[KNN], Pv[KNN];
#pragma unroll
  for (int k = 0; k < KNN; ++k) L[k] = bf2f(lrow[k * 64 + ln]);
#pragma unroll
  for (int k = 0; k < KNN; ++k) Pv[k] = bf2f(lrow[1536 + k * 64 + ln]);
  asm volatile("" ::: "memory");   // all reads of row n before any write

  float mx = -__builtin_inff();
#pragma unroll
  for (int k = 0; k < KNN; ++k) mx = fmaxf(mx, L[k]);
  float ssum = 0.f;
#pragma unroll
  for (int k = 0; k < KNN; ++k) { L[k] = __expf((L[k] - mx) * 0.125f); ssum += L[k]; }
  float inv = 1.0f / ssum;
#pragma unroll
  for (int k = 0; k < KNN; ++k) {
    L[k] *= inv;
    attnF[(size_t)n * DK + k * 64 + ln] = L[k];
  }

  float racc = 0.f;
  for (int k = 0; k < KNN; ++k) {
    int gidx = (b << 13) + sIdx[w][k];
    float xv = x[(size_t)gidx * DM + ln];
    racc = fmaf(L[k], xv + Pv[k], racc);
  }
  sRes[w][ln] = racc;
  WSYNC();
  float oacc = b2[ln] + x[(size_t)n * DM + ln];
#pragma unroll
  for (int o = 0; o < DM; ++o) oacc = fmaf(sRes[w][o], sW2f[ln][o], oacc);
  res[(size_t)n * DM + ln] = oacc;
}

// ---------------------------------------------------------------------------
// K5-full (small-ws fallback): recompute MLP via MFMA, bf16 logits in.
// ---------------------------------------------------------------------------
__global__ __launch_bounds__(256) void finish_full_kernel(
    const float* __restrict__ xyz, const float* __restrict__ x,
    const int* __restrict__ knn,
    const float* __restrict__ Wd1, const float* __restrict__ bd1,
    const float* __restrict__ Wd2, const float* __restrict__ bd2,
    const float* __restrict__ W2, const float* __restrict__ b2,
    const unsigned short* attn16, float* attnF, float* __restrict__ res) {
  __shared__ unsigned short sW1b[4096];
  __shared__ unsigned short sW2bb[4096];
  __shared__ float sW2f[DM][DM + 1];
  __shared__ unsigned short sScr[4][2176];
  __shared__ float sRes[4][64];
  __shared__ int sIdx[4][KNN];
  int tid = threadIdx.x, w = tid >> 6, ln = tid & 63;
  int n = blockIdx.x * 4 + w, b = n >> 13;

  for (int q = tid; q < 4096; q += 256) {
    int row = q >> 6, kk = q & 63;
    int idx = q ^ ((row & 7) << 3);
    sW1b[idx] = (kk < PED) ? f2bf(Wd1[row * PED + kk]) : (unsigned short)0;
    sW2bb[idx] = f2bf(Wd2[q]);
  }
  for (int q = tid; q < DM * DM; q += 256) sW2f[q >> 6][q & 63] = W2[q];
  if (ln < KNN) sIdx[w][ln] = knn[(size_t)n * KNN + ln];
  __syncthreads();

  float qx = xyz[(size_t)n * 3], qy = xyz[(size_t)n * 3 + 1], qz = xyz[(size_t)n * 3 + 2];
  unsigned short* scr = &sScr[w][0];
  pe_fill(scr, xyz, &sIdx[w][0], b << 13, qx, qy, qz, ln);
  mlp_wave(scr, sW1b, sW2bb, bd1, bd2, ln);

  const unsigned short* lrow = attn16 + (size_t)n * 3072;
  float L[KNN];
#pragma unroll
  for (int k = 0; k < KNN; ++k) L[k] = bf2f(lrow[k * 64 + ln]);
  asm volatile("" ::: "memory");
  float mx = -__builtin_inff();
#pragma unroll
  for (int k = 0; k < KNN; ++k) mx = fmaxf(mx, L[k]);
  float ssum = 0.f;
#pragma unroll
  for (int k = 0; k < KNN; ++k) { L[k] = __expf((L[k] - mx) * 0.125f); ssum += L[k]; }
  float inv = 1.0f / ssum;
#pragma unroll
  for (int k = 0; k < KNN; ++k) {
    L[k] *= inv;
    attnF[(size_t)n * DK + k * 64 + ln] = L[k];
  }
  float racc = 0.f;
  for (int k = 0; k < KNN; ++k) {
    int gidx = (b << 13) + sIdx[w][k];
    float xv = x[(size_t)gidx * DM + ln];
    racc = fmaf(L[k], xv + bf2f(scr[k * 68 + ln]), racc);
  }
  sRes[w][ln] = racc;
  WSYNC();
  float oacc = b2[ln] + x[(size_t)n * DM + ln];
#pragma unroll
  for (int o = 0; o < DM; ++o) oacc = fmaf(sRes[w][o], sW2f[ln][o], oacc);
  res[(size_t)n * DM + ln] = oacc;
}

// ---------------------------------------------------------------------------
extern "C" void kernel_launch(void* const* d_in, const int* in_sizes, int n_in,
                              void* d_out, int out_size, void* d_ws, size_t ws_size,
                              hipStream_t stream) {
  const float* features = (const float*)d_in[0];
  const float* xyz = (const float*)d_in[1];
  const float* W1  = (const float*)d_in[2];
  const float* b1  = (const float*)d_in[3];
  const float* W2  = (const float*)d_in[4];
  const float* b2  = (const float*)d_in[5];
  const float* Wd1 = (const float*)d_in[6];
  const float* bd1 = (const float*)d_in[7];
  const float* Wd2 = (const float*)d_in[8];
  const float* bd2 = (const float*)d_in[9];
  const float* Wa  = (const float*)d_in[10];
  const float* ba  = (const float*)d_in[11];

  float* res  = (float*)d_out;                      // [ROWS*64]
  float* attn = (float*)d_out + (size_t)ROWS * DM;  // [ROWS*1536] f32 region
  unsigned short* attn16 = (unsigned short*)attn;   // bf16 view (pitch 3072/row)

  size_t xB   = (size_t)ROWS * DM * 4;              // 8,388,608
  size_t WaB  = (size_t)DK * DK * 2;                // 4,718,592
  size_t used = xB + (size_t)ROWS * KNN * 4;
  float* xbuf = (float*)d_ws;
  int*   knn  = (int*)((char*)d_ws + xB);

  size_t avail = (ws_size > used) ? ws_size - used : 0;
  size_t rowB = (size_t)DK * 2;                     // bf16 row = 3072 B
  bool bigws = avail >= WaB + (size_t)ROWS * rowB;  // 105.4 MB

  // Grid scratch at attn head (16B-aligned); fully consumed by grid_knn
  // before prebuild first writes to the attn region (stream-ordered).
  float4* xyzi = (float4*)attn;                     // [BATCH*NPTS] = 512 KB
  int* gridCS  = (int*)(xyzi + (size_t)BATCH * NPTS);

  hipLaunchKernelGGL(fc1_kernel, dim3(ROWS * DM / 256), dim3(256), 0, stream,
                     features, W1, b1, xbuf);
  hipLaunchKernelGGL(grid_build_kernel, dim3(BATCH), dim3(256), 0, stream,
                     xyz, gridCS, xyzi);
  hipLaunchKernelGGL(grid_knn_kernel, dim3(ROWS / 64), dim3(256), 0, stream,
                     xyzi, gridCS, knn);

  if (bigws) {
    unsigned short* WaBf = (unsigned short*)((char*)d_ws + used);
    unsigned short* preW = (unsigned short*)((char*)d_ws + used + WaB); // 100.7MB
    hipLaunchKernelGGL(prebuild_kernel, dim3(ROWS / 4), dim3(256), 0, stream,
                       xyz, xbuf, knn, Wd1, bd1, Wd2, bd2, preW, attn16);
    {
      int n4 = DK * DK / 4;
      hipLaunchKernelGGL(conv_bf16_kernel, dim3((n4 + 255) / 256), dim3(256), 0, stream,
                         Wa, WaBf, n4);
    }
    hipLaunchKernelGGL(gemm_bf16_kernel, dim3((ROWS / 128) * 12), dim3(256), 0, stream,
                       preW, WaBf, ba, attn16);
    hipLaunchKernelGGL(finish_kernel, dim3(ROWS / 4), dim3(256), 0, stream,
                       xbuf, knn, W2, b2, attn16, attn, res);
  } else {
    unsigned short* WaBf  = (unsigned short*)d_out;
    unsigned short* chunk = (unsigned short*)((char*)d_out + WaB);
    int chunk_rows = (int)((xB - WaB) / rowB) & ~127;   // 1152
    hipLaunchKernelGGL(prebuild_kernel, dim3(ROWS / 4), dim3(256), 0, stream,
                       xyz, xbuf, knn, Wd1, bd1, Wd2, bd2, attn16,
                       (unsigned short*)nullptr);
    {
      int n4 = DK * DK / 4;
      hipLaunchKernelGGL(conv_bf16_kernel, dim3((n4 + 255) / 256), dim3(256), 0, stream,
                         Wa, WaBf, n4);
    }
    {
      int cr0 = (chunk_rows < ROWS) ? chunk_rows : ROWS;
      int nvec = cr0 * (DK * 2 / 16);
      hipLaunchKernelGGL(copy16_kernel, dim3((nvec + 255) / 256), dim3(256), 0, stream,
                         (const uint4*)attn16, (uint4*)chunk, nvec);
    }
    int top = ((ROWS - 1) / chunk_rows) * chunk_rows;
    for (int r0 = top; r0 >= 0; r0 -= chunk_rows) {
      int cr = (ROWS - r0 < chunk_rows) ? (ROWS - r0) : chunk_rows;
      const unsigned short* Aptr =
          (r0 == 0) ? chunk : attn16 + (size_t)r0 * DK;
      hipLaunchKernelGGL(gemm_bf16_kernel, dim3((cr / 128) * 12), dim3(256), 0, stream,
                         Aptr, WaBf, ba, attn16 + (size_t)r0 * 3072);
    }
    hipLaunchKernelGGL(finish_full_kernel, dim3(ROWS / 4), dim3(256), 0, stream,
                       xyz, xbuf, knn, Wd1, bd1, Wd2, bd2, W2, b2,
                       attn16, attn, res);
  }
}

// Round 9
// 879.063 us; speedup vs baseline: 1.4010x; 1.0685x over previous
//
#include <hip/hip_runtime.h>
#include <hip/hip_bf16.h>
#include <stdint.h>

// Problem constants
#define BATCH 4
#define NPTS  8192
#define KNN   24
#define DPT   32     // D_POINTS
#define DM    64     // D_MODEL
#define PED   60     // PE_DIM
#define DK    (DM*KNN)      // 1536
#define ROWS  (BATCH*NPTS)  // 32768

// KNN spatial grid
#define GRIDN 16
#define NCELL (GRIDN*GRIDN*GRIDN)   // 4096
#define CH    0.0625f               // cell width = 1/16 (exact in fp32)

typedef __attribute__((ext_vector_type(8))) short short8;
typedef __attribute__((ext_vector_type(4))) float f32x4;
typedef __attribute__((address_space(3))) unsigned lds_u32;
typedef const __attribute__((address_space(1))) unsigned gbl_u32;

#define WSYNC() __builtin_amdgcn_wave_barrier()

static __device__ __forceinline__ unsigned short f2bf(float f) {
  __hip_bfloat16 h = __float2bfloat16(f);
  return *(unsigned short*)&h;
}
static __device__ __forceinline__ float bf2f(unsigned short u) {
  return __uint_as_float(((unsigned)u) << 16);
}

static __device__ __forceinline__ int cell_coord(float p) {
  int c = (int)(p * (float)GRIDN);
  c = (c < 0) ? 0 : c;
  c = (c > GRIDN - 1) ? GRIDN - 1 : c;
  return c;
}

// ---------------------------------------------------------------------------
// K1: x = features @ W1.T + b1     [ROWS,32] x [64,32]^T -> [ROWS,64]
// ---------------------------------------------------------------------------
__global__ __launch_bounds__(256) void fc1_kernel(
    const float* __restrict__ f, const float* __restrict__ W1,
    const float* __restrict__ b1, float* __restrict__ x) {
  int gid = blockIdx.x * 256 + threadIdx.x;
  int n = gid >> 6, c = gid & 63;
  const float* fr = f + (size_t)n * DPT;
  const float* wr = W1 + c * DPT;
  float acc = b1[c];
#pragma unroll
  for (int i = 0; i < DPT; ++i) acc = fmaf(fr[i], wr[i], acc);
  x[(size_t)n * DM + c] = acc;
}

// ---------------------------------------------------------------------------
// K2a: build per-batch uniform grid over [0,1]^3.
// Scatter writes float4 {x,y,z,bitcast(local idx)} in cell-sorted order.
// ---------------------------------------------------------------------------
__global__ __launch_bounds__(256) void grid_build_kernel(
    const float* __restrict__ xyz, int* __restrict__ cellStart,
    float4* __restrict__ xyzi) {
  __shared__ int cnt[NCELL];     // 16 KB
  __shared__ int partial[256];
  int b = blockIdx.x, tid = threadIdx.x;
  const float* P = xyz + (size_t)b * NPTS * 3;

  for (int i = tid; i < NCELL; i += 256) cnt[i] = 0;
  __syncthreads();
  for (int i = tid; i < NPTS; i += 256) {
    int cx = cell_coord(P[3 * i + 0]);
    int cy = cell_coord(P[3 * i + 1]);
    int cz = cell_coord(P[3 * i + 2]);
    atomicAdd(&cnt[(cx << 8) | (cy << 4) | cz], 1);
  }
  __syncthreads();
  int base = tid * 16, s = 0;
#pragma unroll
  for (int j = 0; j < 16; ++j) s += cnt[base + j];
  partial[tid] = s;
  __syncthreads();
  if (tid == 0) {
    int acc = 0;
    for (int i = 0; i < 256; ++i) { int v = partial[i]; partial[i] = acc; acc += v; }
  }
  __syncthreads();
  int acc = partial[tid];
#pragma unroll
  for (int j = 0; j < 16; ++j) {
    int c = cnt[base + j];
    cnt[base + j] = acc;                          // becomes scatter cursor
    cellStart[b * (NCELL + 1) + base + j] = acc;  // exclusive start
    acc += c;
  }
  if (tid == 255) cellStart[b * (NCELL + 1) + NCELL] = NPTS;
  __syncthreads();
  for (int i = tid; i < NPTS; i += 256) {
    float px = P[3 * i + 0], py = P[3 * i + 1], pz = P[3 * i + 2];
    int cx = cell_coord(px), cy = cell_coord(py), cz = cell_coord(pz);
    int pos = atomicAdd(&cnt[(cx << 8) | (cy << 4) | cz], 1);
    float4 v;
    v.x = px; v.y = py; v.z = pz; v.w = __int_as_float(i);
    xyzi[(size_t)b * NPTS + pos] = v;
  }
}

// ---------------------------------------------------------------------------
// K2b: exact KNN, 4-way segments-in-wave + GROUP-SHARED conservative bound.
// (unchanged from round 8 — verified)
// ---------------------------------------------------------------------------
__global__ __launch_bounds__(256) void grid_knn_kernel(
    const float4* __restrict__ xyzi, const int* __restrict__ cellStart,
    int* __restrict__ knn) {
  __shared__ unsigned long long sKeys[256][KNN];   // 48 KB
  int tid = threadIdx.x;
  int s = tid & 3, ql = tid >> 2;        // segment, block-local query
  int qpos = blockIdx.x * 64 + ql;       // sorted position
  int b = qpos >> 13, j = qpos & 8191;
  const int* cs = cellStart + b * (NCELL + 1);
  const float4* X = xyzi + (size_t)b * NPTS;

  float4 qv = X[j];
  float qx = qv.x, qy = qv.y, qz = qv.z;
  int cx = cell_coord(qx), cy = cell_coord(qy), cz = cell_coord(qz);

  unsigned long long key[KNN];
#pragma unroll
  for (int o = 0; o < KNN; ++o) key[o] = 0x7F800000FFFFFFFFULL;
  float lim = __builtin_inff();

  for (int rho = 0; rho <= GRIDN - 1; ++rho) {
    for (int dz = -rho; dz <= rho; ++dz) {
      int iz = cz + dz;
      if ((unsigned)iz >= GRIDN) continue;
      bool zface = (dz == -rho) || (dz == rho);
      for (int dy = -rho; dy <= rho; ++dy) {
        int iy = cy + dy;
        if ((unsigned)iy >= GRIDN) continue;
        bool face = zface || (dy == -rho) || (dy == rho);
        int dxstep = (rho == 0 || face) ? 1 : (2 * rho);
        for (int dx = -rho; dx <= rho; dx += dxstep) {
          int ix = cx + dx;
          if ((unsigned)ix >= GRIDN) continue;
          float limg = fminf(lim, __shfl_xor(lim, 1, 64));
          limg = fminf(limg, __shfl_xor(limg, 2, 64));
          float bx = ix * CH, by = iy * CH, bz = iz * CH;
          float ex = fmaxf(fmaxf(bx - qx, qx - (bx + CH)), 0.f);
          float ey = fmaxf(fmaxf(by - qy, qy - (by + CH)), 0.f);
          float ez = fmaxf(fmaxf(bz - qz, qz - (bz + CH)), 0.f);
          float dsq = ex * ex + ey * ey + ez * ez;
          if (dsq * 0.99999f >= limg) continue;  // group-uniform skip
          int cid = (ix << 8) | (iy << 4) | iz;
          int s0 = cs[cid], s1 = cs[cid + 1];
          for (int ii = s0 + s; ii < s1; ii += 4) {
            float4 c4 = X[ii];
            float ddx = qx - c4.x;
            float ddy = qy - c4.y;
            float ddz = qz - c4.z;
            double dd = (double)ddx * (double)ddx + (double)ddy * (double)ddy
                      + (double)ddz * (double)ddz;
            float df = (float)dd;
            if (df < fminf(limg, lim)) {
              unsigned long long v =
                  ((unsigned long long)__float_as_uint(df) << 32)
                  | (unsigned)__float_as_int(c4.w);
#pragma unroll
              for (int tt = 0; tt < KNN; ++tt) {
                bool take = v < key[tt];
                unsigned long long old = key[tt];
                key[tt] = take ? v : key[tt];
                v = take ? old : v;
              }
              lim = __uint_as_float((unsigned)(key[KNN - 1] >> 32));
            }
          }
        }
      }
    }
    float limg = fminf(lim, __shfl_xor(lim, 1, 64));
    limg = fminf(limg, __shfl_xor(limg, 2, 64));
    float rb = rho * CH;
    if (limg < rb * rb * 0.999999f) break;
  }
#pragma unroll
  for (int o = 0; o < KNN; ++o) sKeys[tid][o] = key[o];
  __syncthreads();
  if (tid < 64) {                // one thread per query: 4-way sorted merge
    int qpos2 = blockIdx.x * 64 + tid;
    int b2 = qpos2 >> 13, j2 = qpos2 & 8191;
    float4 qv2 = xyzi[(size_t)b2 * NPTS + j2];
    int n = (b2 << 13) + __float_as_int(qv2.w);
    int i0 = 0, i1 = 0, i2 = 0, i3 = 0;
    for (int o = 0; o < KNN; ++o) {
      unsigned long long a = sKeys[tid * 4 + 0][i0];
      unsigned long long bb = sKeys[tid * 4 + 1][i1];
      unsigned long long c = sKeys[tid * 4 + 2][i2];
      unsigned long long d = sKeys[tid * 4 + 3][i3];
      bool ab = a < bb;  unsigned long long m1 = ab ? a : bb;
      bool cd = c < d;   unsigned long long m2 = cd ? c : d;
      bool md = m1 < m2; unsigned long long mv = md ? m1 : m2;
      knn[(size_t)n * KNN + o] = (int)(unsigned)mv;
      if (md) { if (ab) ++i0; else ++i1; }
      else    { if (cd) ++i2; else ++i3; }
    }
  }
}

// ---------------------------------------------------------------------------
__device__ __forceinline__ float pe_elem(int t, float gx, float gy, float gz) {
  const float OM[10] = {1.0f, 0.3981071705534972f, 0.15848931924611134f,
                        0.06309573444801933f, 0.025118864315095794f, 0.01f,
                        0.003981071705534973f, 0.001584893192461114f,
                        0.0006309573444801933f, 0.00025118864315095795f};
  int a = t / 20, r = t % 20;
  float g = (a == 0) ? gx : ((a == 1) ? gy : gz);
  float ang = g * OM[r % 10];
  return (r < 10) ? __sinf(ang) : __cosf(ang);
}

// ---------------------------------------------------------------------------
// Shared MFMA MLP machinery (per-wave, one query per wave).
// scr: PE bf16 [32][64] swizzled -> H bf16 swizzled -> P bf16 [32][68] linear.
// ---------------------------------------------------------------------------
static __device__ __forceinline__ void pe_fill(
    unsigned short* scr, const float* __restrict__ xyz, const int* idxArr,
    int base, float qx, float qy, float qz, int ln) {
  for (int k = 0; k < KNN; ++k) {
    int gidx = base + idxArr[k];
    float gx = qx - xyz[(size_t)gidx * 3 + 0];
    float gy = qy - xyz[(size_t)gidx * 3 + 1];
    float gz = qz - xyz[(size_t)gidx * 3 + 2];
    float v = (ln < PED) ? pe_elem(ln, gx, gy, gz) : 0.f;
    scr[(k * 64 + ln) ^ ((k & 7) << 3)] = f2bf(v);
  }
#pragma unroll
  for (int k = KNN; k < 32; ++k)
    scr[(k * 64 + ln) ^ ((k & 7) << 3)] = 0;
  WSYNC();
}

static __device__ __forceinline__ short8 lds_read8(const unsigned short* p) {
  return *(const short8*)p;
}

static __device__ __forceinline__ void mlp_wave(
    unsigned short* scr, const unsigned short* w1b, const unsigned short* w2b,
    const float* __restrict__ bd1, const float* __restrict__ bd2, int ln) {
  int lrow = ln & 15, lq = ln >> 4;
  short8 af[2][2], bfr[4][2];
  f32x4 acc[2][4];

  // ---- layer 1: H = relu(PE @ Wd1^T + bd1)
#pragma unroll
  for (int mt = 0; mt < 2; ++mt)
#pragma unroll
    for (int ks = 0; ks < 2; ++ks) {
      int row = mt * 16 + lrow;
      af[mt][ks] = lds_read8(scr + ((row * 64 + ks * 32 + lq * 8) ^ ((row & 7) << 3)));
    }
#pragma unroll
  for (int nt = 0; nt < 4; ++nt)
#pragma unroll
    for (int ks = 0; ks < 2; ++ks) {
      int row = nt * 16 + lrow;
      bfr[nt][ks] = lds_read8(w1b + ((row * 64 + ks * 32 + lq * 8) ^ ((row & 7) << 3)));
    }
#pragma unroll
  for (int mt = 0; mt < 2; ++mt)
#pragma unroll
    for (int nt = 0; nt < 4; ++nt) {
      f32x4 a = (f32x4){0.f, 0.f, 0.f, 0.f};
      a = __builtin_amdgcn_mfma_f32_16x16x32_bf16(af[mt][0], bfr[nt][0], a, 0, 0, 0);
      a = __builtin_amdgcn_mfma_f32_16x16x32_bf16(af[mt][1], bfr[nt][1], a, 0, 0, 0);
      acc[mt][nt] = a;
    }
  WSYNC();
#pragma unroll
  for (int mt = 0; mt < 2; ++mt)
#pragma unroll
    for (int nt = 0; nt < 4; ++nt) {
      float b1v = bd1[nt * 16 + lrow];
#pragma unroll
      for (int r = 0; r < 4; ++r) {
        int row = mt * 16 + lq * 4 + r;
        int col = nt * 16 + lrow;
        scr[(row * 64 + col) ^ ((row & 7) << 3)] =
            f2bf(fmaxf(acc[mt][nt][r] + b1v, 0.f));
      }
    }
  WSYNC();
  // ---- layer 2: P = H @ Wd2^T + bd2
#pragma unroll
  for (int mt = 0; mt < 2; ++mt)
#pragma unroll
    for (int ks = 0; ks < 2; ++ks) {
      int row = mt * 16 + lrow;
      af[mt][ks] = lds_read8(scr + ((row * 64 + ks * 32 + lq * 8) ^ ((row & 7) << 3)));
    }
#pragma unroll
  for (int nt = 0; nt < 4; ++nt)
#pragma unroll
    for (int ks = 0; ks < 2; ++ks) {
      int row = nt * 16 + lrow;
      bfr[nt][ks] = lds_read8(w2b + ((row * 64 + ks * 32 + lq * 8) ^ ((row & 7) << 3)));
    }
#pragma unroll
  for (int mt = 0; mt < 2; ++mt)
#pragma unroll
    for (int nt = 0; nt < 4; ++nt) {
      f32x4 a = (f32x4){0.f, 0.f, 0.f, 0.f};
      a = __builtin_amdgcn_mfma_f32_16x16x32_bf16(af[mt][0], bfr[nt][0], a, 0, 0, 0);
      a = __builtin_amdgcn_mfma_f32_16x16x32_bf16(af[mt][1], bfr[nt][1], a, 0, 0, 0);
      acc[mt][nt] = a;
    }
  WSYNC();
#pragma unroll
  for (int mt = 0; mt < 2; ++mt)
#pragma unroll
    for (int nt = 0; nt < 4; ++nt) {
      float b2v = bd2[nt * 16 + lrow];
#pragma unroll
      for (int r = 0; r < 4; ++r) {
        int row = mt * 16 + lq * 4 + r;
        int col = nt * 16 + lrow;
        scr[row * 68 + col] = f2bf(acc[mt][nt][r] + b2v);
      }
    }
  WSYNC();
}

// ---------------------------------------------------------------------------
// K3: pre[n] = bf16(q - kf + pos_enc) -> preOut (packed [ROWS][1536]).
// If P16 != null, also store P bf16 into attn-row upper halves.
// ---------------------------------------------------------------------------
__global__ __launch_bounds__(256) void prebuild_kernel(
    const float* __restrict__ xyz, const float* __restrict__ x,
    const int* __restrict__ knn,
    const float* __restrict__ Wd1, const float* __restrict__ bd1,
    const float* __restrict__ Wd2, const float* __restrict__ bd2,
    unsigned short* __restrict__ preOut, unsigned short* __restrict__ P16) {
  __shared__ unsigned short sW1b[4096];
  __shared__ unsigned short sW2bb[4096];
  __shared__ unsigned short sScr[4][2176];
  __shared__ int sIdx[4][KNN];
  int tid = threadIdx.x, w = tid >> 6, ln = tid & 63;
  int n = blockIdx.x * 4 + w, b = n >> 13;

  for (int q = tid; q < 4096; q += 256) {
    int row = q >> 6, kk = q & 63;
    int idx = q ^ ((row & 7) << 3);
    sW1b[idx] = (kk < PED) ? f2bf(Wd1[row * PED + kk]) : (unsigned short)0;
    sW2bb[idx] = f2bf(Wd2[q]);
  }
  if (ln < KNN) sIdx[w][ln] = knn[(size_t)n * KNN + ln];
  __syncthreads();

  float qx = xyz[(size_t)n * 3], qy = xyz[(size_t)n * 3 + 1], qz = xyz[(size_t)n * 3 + 2];
  float xq = x[(size_t)n * DM + ln];
  unsigned short* scr = &sScr[w][0];

  pe_fill(scr, xyz, &sIdx[w][0], b << 13, qx, qy, qz, ln);
  mlp_wave(scr, sW1b, sW2bb, bd1, bd2, ln);

  for (int k = 0; k < KNN; ++k) {
    int gidx = (b << 13) + sIdx[w][k];
    float kfv = x[(size_t)gidx * DM + ln];
    float p = bf2f(scr[k * 68 + ln]);
    preOut[((size_t)n * KNN + k) * DM + ln] = f2bf(xq - kfv + p);
  }
  if (P16) {
    unsigned short* pd = P16 + (size_t)n * 3072 + 1536;
#pragma unroll
    for (int k = 0; k < KNN; ++k) pd[k * 64 + ln] = scr[k * 68 + ln];
  }
}

// ---------------------------------------------------------------------------
// K4a: f32 -> bf16 convert (vectorized) — Wa only.
// ---------------------------------------------------------------------------
__global__ __launch_bounds__(256) void conv_bf16_kernel(
    const float* __restrict__ src, unsigned short* __restrict__ dst, int n4) {
  int i = blockIdx.x * 256 + threadIdx.x;
  if (i < n4) {
    float4 v = ((const float4*)src)[i];
    ushort4 o;
    o.x = f2bf(v.x); o.y = f2bf(v.y); o.z = f2bf(v.z); o.w = f2bf(v.w);
    ((ushort4*)dst)[i] = o;
  }
}

// 16B copy kernel (fallback path only)
__global__ __launch_bounds__(256) void copy16_kernel(
    const uint4* __restrict__ src, uint4* __restrict__ dst, int nvec) {
  int i = blockIdx.x * 256 + threadIdx.x;
  if (i < nvec) dst[i] = src[i];
}

// ---------------------------------------------------------------------------
// K4b: logits(bf16) = pre_bf16 @ Wa_bf16.T + ba.
// 256x128 tile, 8 waves (512 thr), BK=32, TRIPLE-BUFFERED with counted
// vmcnt(3) (3 gload_lds per wave per stage: 2 A-blocks + 1 B-block).
// 2 blocks/CU (72KB LDS) -> 16 waves/CU; 128 MFMA per barrier window.
// Bijective XCD-chunked swizzle for A-panel L2 locality.
// ---------------------------------------------------------------------------
__global__ __launch_bounds__(512) void gemm_bf16_kernel(
    const unsigned short* __restrict__ A,   // [cr][1536] bf16 packed
    const unsigned short* __restrict__ B,   // Wa bf16 [1536][1536]
    const float* __restrict__ ba,
    unsigned short* __restrict__ Cb) {      // bf16, row pitch 3072 ushorts
  __shared__ unsigned short sA[3][16 * 512];  // 3 x 16KB: 16 blocks x 16r x 32
  __shared__ unsigned short sB[3][8 * 512];   // 3 x  8KB:  8 blocks x 16r x 32
  unsigned nwg = gridDim.x, orig = blockIdx.x;
  unsigned xcd = orig & 7u, qd = nwg >> 3, rr = nwg & 7u;
  unsigned wgid = (xcd < rr ? xcd * (qd + 1) : rr * (qd + 1) + (xcd - rr) * qd)
                + (orig >> 3);
  int mt = wgid / 12, nt = wgid % 12;
  int m0 = mt * 256, n0 = nt * 128;
  int tid = threadIdx.x, w = tid >> 6, L = tid & 63;
  int wr = w >> 1, wc = w & 1;            // 4 x 2 wave grid of 64x64 tiles
  int lrow = L & 15, lq = L >> 4;

  const unsigned short* gA0 = A + (size_t)(m0 + (w * 2) * 16 + lrow) * DK + lq * 8;
  const unsigned short* gA1 = A + (size_t)(m0 + (w * 2 + 1) * 16 + lrow) * DK + lq * 8;
  const unsigned short* gB0 = B + (size_t)(n0 + w * 16 + lrow) * DK + lq * 8;

  f32x4 acc[4][4];
#pragma unroll
  for (int i = 0; i < 4; ++i)
#pragma unroll
    for (int j = 0; j < 4; ++j) acc[i][j] = (f32x4){0.f, 0.f, 0.f, 0.f};

#define STAGE(buf, kt)                                                        \
  {                                                                           \
    __builtin_amdgcn_global_load_lds((gbl_u32*)(gA0 + (kt)),                  \
        (lds_u32*)(&sA[(buf)][(w * 2) * 512]), 16, 0, 0);                     \
    __builtin_amdgcn_global_load_lds((gbl_u32*)(gA1 + (kt)),                  \
        (lds_u32*)(&sA[(buf)][(w * 2 + 1) * 512]), 16, 0, 0);                 \
    __builtin_amdgcn_global_load_lds((gbl_u32*)(gB0 + (kt)),                  \
        (lds_u32*)(&sB[(buf)][w * 512]), 16, 0, 0);                           \
  }

  STAGE(0, 0);
  STAGE(1, 32);

  const int nk = DK / 32;                  // 48
  for (int ki = 0; ki < nk; ++ki) {
    int cur = ki % 3;
    if (ki + 1 < nk) {
      asm volatile("s_waitcnt vmcnt(3)" ::: "memory");
    } else {
      asm volatile("s_waitcnt vmcnt(0)" ::: "memory");
    }
    __builtin_amdgcn_s_barrier();
    asm volatile("" ::: "memory");
    if (ki + 2 < nk) STAGE((ki + 2) % 3, (ki + 2) * 32);
    short8 af[4], bf4[4];
#pragma unroll
    for (int i = 0; i < 4; ++i)
      af[i] = *(const short8*)(&sA[cur][((wr * 4 + i) * 64 + L) * 8]);
#pragma unroll
    for (int j = 0; j < 4; ++j)
      bf4[j] = *(const short8*)(&sB[cur][((wc * 4 + j) * 64 + L) * 8]);
#pragma unroll
    for (int i = 0; i < 4; ++i)
#pragma unroll
      for (int j = 0; j < 4; ++j)
        acc[i][j] = __builtin_amdgcn_mfma_f32_16x16x32_bf16(af[i], bf4[j], acc[i][j], 0, 0, 0);
  }
#undef STAGE

#pragma unroll
  for (int j = 0; j < 4; ++j) {
    int col = n0 + (wc * 4 + j) * 16 + lrow;
    float bav = ba[col];
#pragma unroll
    for (int i = 0; i < 4; ++i) {
      int rbase = m0 + (wr * 4 + i) * 16 + lq * 4;
#pragma unroll
      for (int r = 0; r < 4; ++r)
        Cb[(size_t)(rbase + r) * 3072 + col] = f2bf(acc[i][j][r] + bav);
    }
  }
}

// ---------------------------------------------------------------------------
// K5-lean (big-ws): softmax over K from bf16 logits (attn-row lower half),
// P from upper half; einsum + fc2 + residual; write f32 attn over the row.
// ---------------------------------------------------------------------------
__global__ __launch_bounds__(256) void finish_kernel(
    const float* __restrict__ x, const int* __restrict__ knn,
    const float* __restrict__ W2, const float* __restrict__ b2,
    const unsigned short* attn16, float* attnF, float* __restrict__ res) {
  __shared__ float sW2f[DM][DM + 1];
  __shared__ float sRes[4][64];
  __shared__ int sIdx[4][KNN];
  int tid = threadIdx.x, w = tid >> 6, ln = tid & 63;
  int n = blockIdx.x * 4 + w, b = n >> 13;

  for (int q = tid; q < DM * DM; q += 256) sW2f[q >> 6][q & 63] = W2[q];
  if (ln < KNN) sIdx[w][ln] = knn[(size_t)n * KNN + ln];
  __syncthreads();

  const unsigned short* lrow = attn16 + (size_t)n * 3072;
  float L[KNN], Pv[KNN];
#pragma unroll
  for (int k = 0; k < KNN; ++k) L[k] = bf2f(lrow[k * 64 + ln]);
#pragma unroll
  for (int k = 0; k < KNN; ++k) Pv[k] = bf2f(lrow[1536 + k * 64 + ln]);
  asm volatile("" ::: "memory");   // all reads of row n before any write

  float mx = -__builtin_inff();
#pragma unroll
  for (int k = 0; k < KNN; ++k) mx = fmaxf(mx, L[k]);
  float ssum = 0.f;
#pragma unroll
  for (int k = 0; k < KNN; ++k) { L[k] = __expf((L[k] - mx) * 0.125f); ssum += L[k]; }
  float inv = 1.0f / ssum;
#pragma unroll
  for (int k = 0; k < KNN; ++k) {
    L[k] *= inv;
    attnF[(size_t)n * DK + k * 64 + ln] = L[k];
  }

  float racc = 0.f;
  for (int k = 0; k < KNN; ++k) {
    int gidx = (b << 13) + sIdx[w][k];
    float xv = x[(size_t)gidx * DM + ln];
    racc = fmaf(L[k], xv + Pv[k], racc);
  }
  sRes[w][ln] = racc;
  WSYNC();
  float oacc = b2[ln] + x[(size_t)n * DM + ln];
#pragma unroll
  for (int o = 0; o < DM; ++o) oacc = fmaf(sRes[w][o], sW2f[ln][o], oacc);
  res[(size_t)n * DM + ln] = oacc;
}

// ---------------------------------------------------------------------------
// K5-full (small-ws fallback): recompute MLP via MFMA, bf16 logits in.
// ---------------------------------------------------------------------------
__global__ __launch_bounds__(256) void finish_full_kernel(
    const float* __restrict__ xyz, const float* __restrict__ x,
    const int* __restrict__ knn,
    const float* __restrict__ Wd1, const float* __restrict__ bd1,
    const float* __restrict__ Wd2, const float* __restrict__ bd2,
    const float* __restrict__ W2, const float* __restrict__ b2,
    const unsigned short* attn16, float* attnF, float* __restrict__ res) {
  __shared__ unsigned short sW1b[4096];
  __shared__ unsigned short sW2bb[4096];
  __shared__ float sW2f[DM][DM + 1];
  __shared__ unsigned short sScr[4][2176];
  __shared__ float sRes[4][64];
  __shared__ int sIdx[4][KNN];
  int tid = threadIdx.x, w = tid >> 6, ln = tid & 63;
  int n = blockIdx.x * 4 + w, b = n >> 13;

  for (int q = tid; q < 4096; q += 256) {
    int row = q >> 6, kk = q & 63;
    int idx = q ^ ((row & 7) << 3);
    sW1b[idx] = (kk < PED) ? f2bf(Wd1[row * PED + kk]) : (unsigned short)0;
    sW2bb[idx] = f2bf(Wd2[q]);
  }
  for (int q = tid; q < DM * DM; q += 256) sW2f[q >> 6][q & 63] = W2[q];
  if (ln < KNN) sIdx[w][ln] = knn[(size_t)n * KNN + ln];
  __syncthreads();

  float qx = xyz[(size_t)n * 3], qy = xyz[(size_t)n * 3 + 1], qz = xyz[(size_t)n * 3 + 2];
  unsigned short* scr = &sScr[w][0];
  pe_fill(scr, xyz, &sIdx[w][0], b << 13, qx, qy, qz, ln);
  mlp_wave(scr, sW1b, sW2bb, bd1, bd2, ln);

  const unsigned short* lrow = attn16 + (size_t)n * 3072;
  float L[KNN];
#pragma unroll
  for (int k = 0; k < KNN; ++k) L[k] = bf2f(lrow[k * 64 + ln]);
  asm volatile("" ::: "memory");
  float mx = -__builtin_inff();
#pragma unroll
  for (int k = 0; k < KNN; ++k) mx = fmaxf(mx, L[k]);
  float ssum = 0.f;
#pragma unroll
  for (int k = 0; k < KNN; ++k) { L[k] = __expf((L[k] - mx) * 0.125f); ssum += L[k]; }
  float inv = 1.0f / ssum;
#pragma unroll
  for (int k = 0; k < KNN; ++k) {
    L[k] *= inv;
    attnF[(size_t)n * DK + k * 64 + ln] = L[k];
  }
  float racc = 0.f;
  for (int k = 0; k < KNN; ++k) {
    int gidx = (b << 13) + sIdx[w][k];
    float xv = x[(size_t)gidx * DM + ln];
    racc = fmaf(L[k], xv + bf2f(scr[k * 68 + ln]), racc);
  }
  sRes[w][ln] = racc;
  WSYNC();
  float oacc = b2[ln] + x[(size_t)n * DM + ln];
#pragma unroll
  for (int o = 0; o < DM; ++o) oacc = fmaf(sRes[w][o], sW2f[ln][o], oacc);
  res[(size_t)n * DM + ln] = oacc;
}

// ---------------------------------------------------------------------------
extern "C" void kernel_launch(void* const* d_in, const int* in_sizes, int n_in,
                              void* d_out, int out_size, void* d_ws, size_t ws_size,
                              hipStream_t stream) {
  const float* features = (const float*)d_in[0];
  const float* xyz = (const float*)d_in[1];
  const float* W1  = (const float*)d_in[2];
  const float* b1  = (const float*)d_in[3];
  const float* W2  = (const float*)d_in[4];
  const float* b2  = (const float*)d_in[5];
  const float* Wd1 = (const float*)d_in[6];
  const float* bd1 = (const float*)d_in[7];
  const float* Wd2 = (const float*)d_in[8];
  const float* bd2 = (const float*)d_in[9];
  const float* Wa  = (const float*)d_in[10];
  const float* ba  = (const float*)d_in[11];

  float* res  = (float*)d_out;                      // [ROWS*64]
  float* attn = (float*)d_out + (size_t)ROWS * DM;  // [ROWS*1536] f32 region
  unsigned short* attn16 = (unsigned short*)attn;   // bf16 view (pitch 3072/row)

  size_t xB   = (size_t)ROWS * DM * 4;              // 8,388,608
  size_t WaB  = (size_t)DK * DK * 2;                // 4,718,592
  size_t used = xB + (size_t)ROWS * KNN * 4;
  float* xbuf = (float*)d_ws;
  int*   knn  = (int*)((char*)d_ws + xB);

  size_t avail = (ws_size > used) ? ws_size - used : 0;
  size_t rowB = (size_t)DK * 2;                     // bf16 row = 3072 B
  bool bigws = avail >= WaB + (size_t)ROWS * rowB;  // 105.4 MB

  // Grid scratch at attn head (16B-aligned); fully consumed by grid_knn
  // before prebuild first writes to the attn region (stream-ordered).
  float4* xyzi = (float4*)attn;                     // [BATCH*NPTS] = 512 KB
  int* gridCS  = (int*)(xyzi + (size_t)BATCH * NPTS);

  hipLaunchKernelGGL(fc1_kernel, dim3(ROWS * DM / 256), dim3(256), 0, stream,
                     features, W1, b1, xbuf);
  hipLaunchKernelGGL(grid_build_kernel, dim3(BATCH), dim3(256), 0, stream,
                     xyz, gridCS, xyzi);
  hipLaunchKernelGGL(grid_knn_kernel, dim3(ROWS / 64), dim3(256), 0, stream,
                     xyzi, gridCS, knn);

  if (bigws) {
    unsigned short* WaBf = (unsigned short*)((char*)d_ws + used);
    unsigned short* preW = (unsigned short*)((char*)d_ws + used + WaB); // 100.7MB
    hipLaunchKernelGGL(prebuild_kernel, dim3(ROWS / 4), dim3(256), 0, stream,
                       xyz, xbuf, knn, Wd1, bd1, Wd2, bd2, preW, attn16);
    {
      int n4 = DK * DK / 4;
      hipLaunchKernelGGL(conv_bf16_kernel, dim3((n4 + 255) / 256), dim3(256), 0, stream,
                         Wa, WaBf, n4);
    }
    hipLaunchKernelGGL(gemm_bf16_kernel, dim3((ROWS / 256) * 12), dim3(512), 0, stream,
                       preW, WaBf, ba, attn16);
    hipLaunchKernelGGL(finish_kernel, dim3(ROWS / 4), dim3(256), 0, stream,
                       xbuf, knn, W2, b2, attn16, attn, res);
  } else {
    unsigned short* WaBf  = (unsigned short*)d_out;
    unsigned short* chunk = (unsigned short*)((char*)d_out + WaB);
    int chunk_rows = (int)((xB - WaB) / rowB) & ~255;   // 1024 (mult of 256)
    hipLaunchKernelGGL(prebuild_kernel, dim3(ROWS / 4), dim3(256), 0, stream,
                       xyz, xbuf, knn, Wd1, bd1, Wd2, bd2, attn16,
                       (unsigned short*)nullptr);
    {
      int n4 = DK * DK / 4;
      hipLaunchKernelGGL(conv_bf16_kernel, dim3((n4 + 255) / 256), dim3(256), 0, stream,
                         Wa, WaBf, n4);
    }
    {
      int cr0 = (chunk_rows < ROWS) ? chunk_rows : ROWS;
      int nvec = cr0 * (DK * 2 / 16);
      hipLaunchKernelGGL(copy16_kernel, dim3((nvec + 255) / 256), dim3(256), 0, stream,
                         (const uint4*)attn16, (uint4*)chunk, nvec);
    }
    int top = ((ROWS - 1) / chunk_rows) * chunk_rows;
    for (int r0 = top; r0 >= 0; r0 -= chunk_rows) {
      int cr = (ROWS - r0 < chunk_rows) ? (ROWS - r0) : chunk_rows;
      const unsigned short* Aptr =
          (r0 == 0) ? chunk : attn16 + (size_t)r0 * DK;
      hipLaunchKernelGGL(gemm_bf16_kernel, dim3((cr / 256) * 12), dim3(512), 0, stream,
                         Aptr, WaBf, ba, attn16 + (size_t)r0 * 3072);
    }
    hipLaunchKernelGGL(finish_full_kernel, dim3(ROWS / 4), dim3(256), 0, stream,
                       xyz, xbuf, knn, Wd1, bd1, Wd2, bd2, W2, b2,
                       attn16, attn, res);
  }
}